// Round 1
// baseline (1140.509 us; speedup 1.0000x reference)
//
#include <hip/hip_runtime.h>

// QANet attention layer on MI355X (gfx950).
// Shapes: B=40,S=128,H=768, NP=100, PL=20, HID=100, N=4000 sequences.
// Pipeline: biLSTM gates via bf16 MFMA (per-step fused GEMM) -> cell (f32)
//           -> proj MFMA -> trilinear scores (f32 tiled) -> softmax x2 (f32)
//           -> weight_cs/probs/weighted_context (f32 tiled) -> cat (bf16)
//           -> attp MFMA + relu + residual -> LayerNorm (f32, in-place d_out).

typedef unsigned short ushort_t;
typedef unsigned int u32;
typedef __attribute__((ext_vector_type(8))) short short8;
typedef __attribute__((ext_vector_type(4))) float f32x4;

__device__ __forceinline__ ushort_t f2bf(float f) {
  u32 x = __builtin_bit_cast(u32, f);
  u32 r = (x + 0x7fffu + ((x >> 16) & 1u)) >> 16;
  return (ushort_t)r;
}

// ---------------- prep / convert kernels ----------------

__global__ void prep_weights(const float* __restrict__ Wih_f, const float* __restrict__ Wih_b,
                             const float* __restrict__ Whh_f, const float* __restrict__ Whh_b,
                             const float* __restrict__ bih_f, const float* __restrict__ bhh_f,
                             const float* __restrict__ bih_b, const float* __restrict__ bhh_b,
                             const float* __restrict__ projW, const float* __restrict__ attpW,
                             ushort_t* __restrict__ wihcat, ushort_t* __restrict__ whhcat,
                             float* __restrict__ biascat, ushort_t* __restrict__ projw_bf,
                             ushort_t* __restrict__ attpw_bf) {
  const int TOT = 614400 + 102400 + 800 + 196608 + 2359296;
  for (int idx = blockIdx.x * 256 + threadIdx.x; idx < TOT; idx += gridDim.x * 256) {
    if (idx < 614400) {                       // Wih cat [800][768]
      int g = idx / 768, k = idx % 768;
      float v = g < 400 ? Wih_f[g * 768 + k] : Wih_b[(g - 400) * 768 + k];
      wihcat[idx] = f2bf(v);
    } else if (idx < 716800) {                // Whh cat padded [800][128]
      int e = idx - 614400; int g = e / 128, j = e % 128;
      float v = 0.f;
      if (j < 100) v = g < 400 ? Whh_f[g * 100 + j] : Whh_b[(g - 400) * 100 + j];
      whhcat[e] = f2bf(v);
    } else if (idx < 717600) {                // bias cat [800]
      int g = idx - 716800;
      biascat[g] = g < 400 ? bih_f[g] + bhh_f[g] : bih_b[g - 400] + bhh_b[g - 400];
    } else if (idx < 914208) {                // projW padded [768][256]
      int e = idx - 717600; int o = e / 256, j = e % 256;
      float v = 0.f;
      if (j < 100) v = projW[o * 200 + j];
      else if (j >= 128 && j < 228) v = projW[o * 200 + 100 + (j - 128)];
      projw_bf[e] = f2bf(v);
    } else {                                  // attpW [768][3072]
      int e = idx - 914208;
      attpw_bf[e] = f2bf(attpW[e]);
    }
  }
}

__global__ void convert_x(const float4* __restrict__ x, ushort4* __restrict__ xb, int n4) {
  for (int i = blockIdx.x * 256 + threadIdx.x; i < n4; i += gridDim.x * 256) {
    float4 v = x[i];
    ushort4 o;
    o.x = f2bf(v.x); o.y = f2bf(v.y); o.z = f2bf(v.z); o.w = f2bf(v.w);
    xb[i] = o;
  }
}

__global__ void convert_slice(const float* __restrict__ x, ushort_t* __restrict__ xs, int t) {
  // xs[2][4000][768] ; dir0 uses time t, dir1 uses time 19-t
  const int TOT = 2 * 4000 * 768;
  for (int i = blockIdx.x * 256 + threadIdx.x; i < TOT; i += gridDim.x * 256) {
    int dir = i / (4000 * 768);
    int r = (i / 768) % 4000;
    int k = i % 768;
    int tt = dir ? (19 - t) : t;
    xs[i] = f2bf(x[(size_t)r * 15360 + (size_t)tt * 768 + k]);
  }
}

// ---------------- MFMA GEMM kernels (bf16 in, f32 out) ----------------
// LDS tiles 64x64 bf16, XOR swizzle on 16B slots: phys_slot = slot ^ (row&7).

__global__ __launch_bounds__(256) void gemm_gates(
    const ushort_t* __restrict__ A1f, const ushort_t* __restrict__ A1b, int lda1,
    const ushort_t* __restrict__ Hb,   // h_bf16 [2][4000][128]
    const ushort_t* __restrict__ Wih,  // [800][768]
    const ushort_t* __restrict__ Whh,  // [800][128]
    float* __restrict__ Cout)          // gates [4000][800]
{
  __shared__ __align__(16) ushort_t ldsA[64 * 64];
  __shared__ __align__(16) ushort_t ldsB[64 * 64];
  int dir = blockIdx.z;
  int bm = blockIdx.x, bn = blockIdx.y;
  int tid = threadIdx.x;
  const ushort_t* A1 = dir ? A1b : A1f;
  const ushort_t* A2 = Hb + (size_t)dir * 4000 * 128;
  const ushort_t* B1 = Wih + (size_t)dir * 400 * 768;
  const ushort_t* B2 = Whh + (size_t)dir * 400 * 128;
  f32x4 z4 = {0.f, 0.f, 0.f, 0.f};
  f32x4 acc[2][2] = {{z4, z4}, {z4, z4}};
  int lane = tid & 63, w = tid >> 6, wr = w >> 1, wc = w & 1;
  int l15 = lane & 15, lk = lane >> 4;
  for (int kt = 0; kt < 14; ++kt) {   // 12 iters over x-part (K=768), 2 over h-part (K=128)
    __syncthreads();
    #pragma unroll
    for (int i = 0; i < 2; ++i) {
      int c = tid + 256 * i;           // 512 chunks of 16B
      int r = c >> 3, s = c & 7;
      int m = bm * 64 + r;
      uint4 av = {0u, 0u, 0u, 0u};
      if (m < 4000) {
        if (kt < 12) av = *reinterpret_cast<const uint4*>(A1 + (size_t)m * lda1 + kt * 64 + s * 8);
        else         av = *reinterpret_cast<const uint4*>(A2 + (size_t)m * 128 + (kt - 12) * 64 + s * 8);
      }
      *reinterpret_cast<uint4*>(&ldsA[r * 64 + ((s ^ (r & 7)) << 3)]) = av;
      int n = bn * 64 + r;
      uint4 bv = {0u, 0u, 0u, 0u};
      if (n < 400) {
        if (kt < 12) bv = *reinterpret_cast<const uint4*>(B1 + (size_t)n * 768 + kt * 64 + s * 8);
        else         bv = *reinterpret_cast<const uint4*>(B2 + (size_t)n * 128 + (kt - 12) * 64 + s * 8);
      }
      *reinterpret_cast<uint4*>(&ldsB[r * 64 + ((s ^ (r & 7)) << 3)]) = bv;
    }
    __syncthreads();
    #pragma unroll
    for (int ks = 0; ks < 2; ++ks) {
      short8 af[2], bfv[2];
      #pragma unroll
      for (int f = 0; f < 2; ++f) {
        int row = wr * 32 + f * 16 + l15, slot = ks * 4 + lk;
        af[f] = *reinterpret_cast<const short8*>(&ldsA[row * 64 + ((slot ^ (row & 7)) << 3)]);
      }
      #pragma unroll
      for (int f = 0; f < 2; ++f) {
        int row = wc * 32 + f * 16 + l15, slot = ks * 4 + lk;
        bfv[f] = *reinterpret_cast<const short8*>(&ldsB[row * 64 + ((slot ^ (row & 7)) << 3)]);
      }
      #pragma unroll
      for (int fm = 0; fm < 2; ++fm)
        #pragma unroll
        for (int fn = 0; fn < 2; ++fn)
          acc[fm][fn] = __builtin_amdgcn_mfma_f32_16x16x32_bf16(af[fm], bfv[fn], acc[fm][fn], 0, 0, 0);
    }
  }
  #pragma unroll
  for (int fm = 0; fm < 2; ++fm)
    #pragma unroll
    for (int fn = 0; fn < 2; ++fn)
      #pragma unroll
      for (int r = 0; r < 4; ++r) {
        int m = bm * 64 + wr * 32 + fm * 16 + lk * 4 + r;   // C/D: row=(lane>>4)*4+reg
        int n = bn * 64 + wc * 32 + fn * 16 + l15;          //      col=lane&15
        if (m < 4000 && n < 400) Cout[(size_t)m * 800 + dir * 400 + n] = acc[fm][fn][r];
      }
}

__global__ __launch_bounds__(256) void gemm_bias_act(
    const ushort_t* __restrict__ A, int lda,
    const ushort_t* __restrict__ B, int ldb,
    int M, int N, int KT,
    const float* __restrict__ bias,
    const float* __restrict__ resid,   // nullable; row stride ldc
    float* __restrict__ C, int ldc)
{
  __shared__ __align__(16) ushort_t ldsA[64 * 64];
  __shared__ __align__(16) ushort_t ldsB[64 * 64];
  int bm = blockIdx.x, bn = blockIdx.y;
  int tid = threadIdx.x;
  f32x4 z4 = {0.f, 0.f, 0.f, 0.f};
  f32x4 acc[2][2] = {{z4, z4}, {z4, z4}};
  int lane = tid & 63, w = tid >> 6, wr = w >> 1, wc = w & 1;
  int l15 = lane & 15, lk = lane >> 4;
  for (int kt = 0; kt < KT; ++kt) {
    __syncthreads();
    #pragma unroll
    for (int i = 0; i < 2; ++i) {
      int c = tid + 256 * i;
      int r = c >> 3, s = c & 7;
      int m = bm * 64 + r;
      uint4 av = {0u, 0u, 0u, 0u};
      if (m < M) av = *reinterpret_cast<const uint4*>(A + (size_t)m * lda + kt * 64 + s * 8);
      *reinterpret_cast<uint4*>(&ldsA[r * 64 + ((s ^ (r & 7)) << 3)]) = av;
      int n = bn * 64 + r;
      uint4 bv = {0u, 0u, 0u, 0u};
      if (n < N) bv = *reinterpret_cast<const uint4*>(B + (size_t)n * ldb + kt * 64 + s * 8);
      *reinterpret_cast<uint4*>(&ldsB[r * 64 + ((s ^ (r & 7)) << 3)]) = bv;
    }
    __syncthreads();
    #pragma unroll
    for (int ks = 0; ks < 2; ++ks) {
      short8 af[2], bfv[2];
      #pragma unroll
      for (int f = 0; f < 2; ++f) {
        int row = wr * 32 + f * 16 + l15, slot = ks * 4 + lk;
        af[f] = *reinterpret_cast<const short8*>(&ldsA[row * 64 + ((slot ^ (row & 7)) << 3)]);
      }
      #pragma unroll
      for (int f = 0; f < 2; ++f) {
        int row = wc * 32 + f * 16 + l15, slot = ks * 4 + lk;
        bfv[f] = *reinterpret_cast<const short8*>(&ldsB[row * 64 + ((slot ^ (row & 7)) << 3)]);
      }
      #pragma unroll
      for (int fm = 0; fm < 2; ++fm)
        #pragma unroll
        for (int fn = 0; fn < 2; ++fn)
          acc[fm][fn] = __builtin_amdgcn_mfma_f32_16x16x32_bf16(af[fm], bfv[fn], acc[fm][fn], 0, 0, 0);
    }
  }
  #pragma unroll
  for (int fm = 0; fm < 2; ++fm)
    #pragma unroll
    for (int fn = 0; fn < 2; ++fn)
      #pragma unroll
      for (int r = 0; r < 4; ++r) {
        int m = bm * 64 + wr * 32 + fm * 16 + lk * 4 + r;
        int n = bn * 64 + wc * 32 + fn * 16 + l15;
        if (m < M && n < N) {
          float v = acc[fm][fn][r] + bias[n];
          v = fmaxf(v, 0.f);
          if (resid) v += resid[(size_t)m * ldc + n];
          C[(size_t)m * ldc + n] = v;
        }
      }
}

// ---------------- LSTM cell ----------------

__global__ void lstm_cell(const float* __restrict__ gates, const float* __restrict__ biascat,
                          float* __restrict__ c_st, ushort_t* __restrict__ h_bf,
                          ushort_t* __restrict__ hcat, int is_last) {
  int idx = blockIdx.x * blockDim.x + threadIdx.x;   // 2*4000*100
  if (idx >= 800000) return;
  int dir = idx / 400000;
  int rem = idx - dir * 400000;
  int n = rem / 100, j = rem - n * 100;
  const float* g = gates + (size_t)n * 800 + dir * 400;
  const float* bb = biascat + dir * 400;
  float gi = g[j] + bb[j];
  float gf = g[100 + j] + bb[100 + j];
  float gg = g[200 + j] + bb[200 + j];
  float go = g[300 + j] + bb[300 + j];
  float si = 1.f / (1.f + expf(-gi));
  float sf = 1.f / (1.f + expf(-gf));
  float so = 1.f / (1.f + expf(-go));
  float cp = c_st[idx];
  float cn = sf * cp + si * tanhf(gg);
  float hn = so * tanhf(cn);
  c_st[idx] = cn;
  h_bf[(size_t)dir * 4000 * 128 + (size_t)n * 128 + j] = f2bf(hn);
  if (is_last) hcat[(size_t)n * 256 + dir * 128 + j] = f2bf(hn);
}

// ---------------- small f32 kernels ----------------

__global__ void rowdot(const float* __restrict__ X, int ld, const float* __restrict__ w,
                       const float* __restrict__ b0, float* __restrict__ out, int nrows) {
  int row = blockIdx.x;
  if (row >= nrows) return;
  int lane = threadIdx.x;   // 64
  const float* x = X + (size_t)row * ld;
  float s = 0.f;
  for (int k = lane; k < 768; k += 64) s += x[k] * w[k];
  for (int off = 32; off; off >>= 1) s += __shfl_down(s, off);
  if (lane == 0) out[row] = s + b0[0];
}

__global__ void bertw3_k(const float* __restrict__ bert, const float* __restrict__ W3,
                         float* __restrict__ out) {
  const int TOT = 40 * 128 * 768;
  for (int i = blockIdx.x * 256 + threadIdx.x; i < TOT; i += gridDim.x * 256)
    out[i] = bert[i] * W3[i % 768];
}

template <int TRANSB, int EPI>
__global__ __launch_bounds__(256) void bgemm(
    const float* __restrict__ A, long long sA, int lda,
    const float* __restrict__ B, long long sB, int ldb,
    float* __restrict__ C, long long sC, int ldc,
    int M, int N, int K,
    const float* __restrict__ p1, const float* __restrict__ p2,
    const int* __restrict__ amask, const int* __restrict__ cmask) {
  int b = blockIdx.z;
  __shared__ float As[32][33], Bs[32][33];
  int tx = threadIdx.x, ty = threadIdx.y;
  int t = ty * 16 + tx;
  int n0 = blockIdx.x * 32, m0 = blockIdx.y * 32;
  const float* Ab = A + (size_t)b * sA;
  const float* Bb = B + (size_t)b * sB;
  float c00 = 0, c01 = 0, c10 = 0, c11 = 0;
  for (int k0 = 0; k0 < K; k0 += 32) {
    __syncthreads();
    #pragma unroll
    for (int i = 0; i < 4; ++i) {
      int e = t + i * 256;
      int r = e >> 5, q = e & 31;
      {
        int m = m0 + r, k = k0 + q;
        As[r][q] = (m < M && k < K) ? Ab[(size_t)m * lda + k] : 0.f;
      }
      if (TRANSB) {
        int n = n0 + r, k = k0 + q;
        Bs[q][r] = (n < N && k < K) ? Bb[(size_t)n * ldb + k] : 0.f;
      } else {
        int k = k0 + r, n = n0 + q;
        Bs[r][q] = (k < K && n < N) ? Bb[(size_t)k * ldb + n] : 0.f;
      }
    }
    __syncthreads();
    #pragma unroll 8
    for (int k = 0; k < 32; ++k) {
      float a0 = As[ty][k], a1 = As[ty + 16][k];
      float b0 = Bs[k][tx], b1 = Bs[k][tx + 16];
      c00 += a0 * b0; c01 += a0 * b1;
      c10 += a1 * b0; c11 += a1 * b1;
    }
  }
  float cc[2][2] = {{c00, c01}, {c10, c11}};
  #pragma unroll
  for (int i = 0; i < 2; ++i)
    #pragma unroll
    for (int j = 0; j < 2; ++j) {
      int m = m0 + ty + 16 * i, n = n0 + tx + 16 * j;
      if (m < M && n < N) {
        float v = cc[i][j];
        if (EPI == 1) {
          v += p1[b * M + m] + p2[b * N + n];
          v += (1.f - (float)amask[b * M + m]) * -10000.f;
          v += (1.f - (float)cmask[b * N + n]) * -10000.f;
        }
        C[(size_t)b * sC + (size_t)m * ldc + n] = v;
      }
    }
}

__global__ void softmax_p(const float* __restrict__ total, float* __restrict__ out) {
  int row = blockIdx.x;   // 5120 = b*128+s
  int lane = threadIdx.x; // 64
  const float* x = total + (size_t)row * 100;
  float e0 = x[lane];
  bool has1 = (lane + 64) < 100;
  float e1 = has1 ? x[lane + 64] : -3.4e38f;
  float m = fmaxf(e0, e1);
  for (int off = 32; off; off >>= 1) m = fmaxf(m, __shfl_xor(m, off));
  float s0 = expf(e0 - m), s1 = has1 ? expf(e1 - m) : 0.f;
  float s = s0 + s1;
  for (int off = 32; off; off >>= 1) s += __shfl_xor(s, off);
  float inv = 1.f / s;
  float* o = out + (size_t)row * 100;
  o[lane] = s0 * inv;
  if (has1) o[lane + 64] = s1 * inv;
}

__global__ void softmax_s(const float* __restrict__ total, float* __restrict__ out) {
  int col = blockIdx.x;   // 4000 = b*100+p
  int b = col / 100, p = col - b * 100;
  int lane = threadIdx.x;
  const float* base = total + (size_t)b * 12800 + p;
  float e0 = base[lane * 100], e1 = base[(lane + 64) * 100];
  float m = fmaxf(e0, e1);
  for (int off = 32; off; off >>= 1) m = fmaxf(m, __shfl_xor(m, off));
  float s0 = expf(e0 - m), s1 = expf(e1 - m);
  float s = s0 + s1;
  for (int off = 32; off; off >>= 1) s += __shfl_xor(s, off);
  float inv = 1.f / s;
  float* o = out + (size_t)b * 12800 + p;
  o[lane * 100] = s0 * inv;
  o[(lane + 64) * 100] = s1 * inv;
}

__global__ void catk(const float* __restrict__ bert, const float* __restrict__ wcs,
                     const float* __restrict__ wctx, ushort_t* __restrict__ cat) {
  const int TOT = 5120 * 3072;
  for (int i = blockIdx.x * 256 + threadIdx.x; i < TOT; i += gridDim.x * 256) {
    int row = i / 3072, col = i - row * 3072;
    int seg = col >> 9 >> 1;            // col/1024? no -- compute directly below
    seg = col / 768;
    int h = col - seg * 768;
    size_t e = (size_t)row * 768 + h;
    float v;
    if (seg == 0) v = bert[e];
    else if (seg == 1) v = wcs[e];
    else if (seg == 2) v = bert[e] * wcs[e];
    else v = bert[e] * wctx[e];
    cat[i] = f2bf(v);
  }
}

__global__ __launch_bounds__(256) void layernorm(float* __restrict__ X,
                                                 const float* __restrict__ w,
                                                 const float* __restrict__ bta) {
  int row = blockIdx.x;   // 5120
  float* x = X + (size_t)row * 768;
  int t = threadIdx.x;
  float v[3];
  float s = 0.f;
  #pragma unroll
  for (int i = 0; i < 3; ++i) { v[i] = x[t + 256 * i]; s += v[i]; }
  __shared__ float red[256];
  red[t] = s; __syncthreads();
  for (int off = 128; off; off >>= 1) { if (t < off) red[t] += red[t + off]; __syncthreads(); }
  float mean = red[0] * (1.f / 768.f);
  __syncthreads();
  float q = 0.f;
  #pragma unroll
  for (int i = 0; i < 3; ++i) { float d = v[i] - mean; q += d * d; }
  red[t] = q; __syncthreads();
  for (int off = 128; off; off >>= 1) { if (t < off) red[t] += red[t + off]; __syncthreads(); }
  float inv = rsqrtf(red[0] * (1.f / 768.f) + 1e-12f);
  #pragma unroll
  for (int i = 0; i < 3; ++i) {
    int k = t + 256 * i;
    x[k] = w[k] * ((v[i] - mean) * inv) + bta[k];
  }
}

// ---------------- host orchestration ----------------

extern "C" void kernel_launch(void* const* d_in, const int* in_sizes, int n_in,
                              void* d_out, int out_size, void* d_ws, size_t ws_size,
                              hipStream_t stream) {
  (void)in_sizes; (void)n_in; (void)out_size;
  const float* bert  = (const float*)d_in[0];
  const float* cmn   = (const float*)d_in[1];
  const int*   amask = (const int*)d_in[2];
  const int*   cmask = (const int*)d_in[3];
  const float* Wih_f = (const float*)d_in[8];
  const float* Whh_f = (const float*)d_in[9];
  const float* bih_f = (const float*)d_in[10];
  const float* bhh_f = (const float*)d_in[11];
  const float* Wih_b = (const float*)d_in[12];
  const float* Whh_b = (const float*)d_in[13];
  const float* bih_b = (const float*)d_in[14];
  const float* bhh_b = (const float*)d_in[15];
  const float* projW = (const float*)d_in[16];
  const float* projb = (const float*)d_in[17];
  const float* W1w   = (const float*)d_in[18];
  const float* W1b   = (const float*)d_in[19];
  const float* W2w   = (const float*)d_in[20];
  const float* W2b   = (const float*)d_in[21];
  const float* W3    = (const float*)d_in[22];
  const float* attpW = (const float*)d_in[23];
  const float* attpb = (const float*)d_in[24];
  const float* lnw   = (const float*)d_in[25];
  const float* lnb   = (const float*)d_in[26];

  char* base = (char*)d_ws;
  size_t off = 0;
  auto alloc = [&](size_t bytes) -> char* {
    char* r = base + off;
    off += (bytes + 255) & ~(size_t)255;
    return r;
  };
  ushort_t* wihcat   = (ushort_t*)alloc(800 * 768 * 2);
  ushort_t* whhcat   = (ushort_t*)alloc(800 * 128 * 2);
  float*    biascat  = (float*)alloc(800 * 4);
  ushort_t* projw_bf = (ushort_t*)alloc(768 * 256 * 2);
  ushort_t* attpw_bf = (ushort_t*)alloc(768 * 3072 * 2);
  ushort_t* h_bf     = (ushort_t*)alloc(2 * 4000 * 128 * 2);
  float*    c_st     = (float*)alloc(2 * 4000 * 100 * 4);
  float*    gates    = (float*)alloc((size_t)4000 * 800 * 4);
  ushort_t* hcat     = (ushort_t*)alloc(4000 * 256 * 2);
  float*    cs       = (float*)alloc((size_t)4000 * 768 * 4);
  float*    part1    = (float*)alloc(5120 * 4);
  float*    part2    = (float*)alloc(4000 * 4);
  float*    total_s  = (float*)alloc((size_t)40 * 128 * 100 * 4);
  float*    cs_att   = (float*)alloc((size_t)40 * 128 * 100 * 4);
  float*    ctx_att  = (float*)alloc((size_t)40 * 128 * 100 * 4);

  // overlay region: during LSTM holds bf16 x (path A) or per-step slices (path B);
  // afterwards holds the late attention buffers.
  char* rx = base + off;
  size_t offX = 0;
  auto allocX = [&](size_t bytes) -> char* {
    char* r = rx + offX;
    offX += (bytes + 255) & ~(size_t)255;
    return r;
  };
  float*    bertW3 = (float*)allocX((size_t)40 * 128 * 768 * 4);
  float*    probs  = (float*)allocX((size_t)40 * 128 * 128 * 4);
  float*    wcs    = (float*)allocX((size_t)40 * 128 * 768 * 4);
  float*    wctx   = (float*)allocX((size_t)40 * 128 * 768 * 4);
  ushort_t* cat    = (ushort_t*)allocX((size_t)5120 * 3072 * 2);
  size_t lateSize = offX;

  const size_t XBF_BYTES = (size_t)4000 * 20 * 768 * 2;   // 122.88 MB
  const size_t XSL_BYTES = (size_t)2 * 4000 * 768 * 2;    // 12.29 MB
  size_t needA = off + (XBF_BYTES > lateSize ? XBF_BYTES : lateSize);
  bool pathA = ws_size >= needA;
  ushort_t* x_bf   = (ushort_t*)rx;   // path A: [4000][20][768]
  ushort_t* xslice = (ushort_t*)rx;   // path B: [2][4000][768]
  (void)XSL_BYTES;

  // zero LSTM state + padded buffers (every call: harness poisons ws before timing)
  hipMemsetAsync(h_bf, 0, (size_t)2 * 4000 * 128 * 2, stream);
  hipMemsetAsync(c_st, 0, (size_t)2 * 4000 * 100 * 4, stream);
  hipMemsetAsync(hcat, 0, (size_t)4000 * 256 * 2, stream);

  prep_weights<<<512, 256, 0, stream>>>(Wih_f, Wih_b, Whh_f, Whh_b, bih_f, bhh_f, bih_b, bhh_b,
                                        projW, attpW, wihcat, whhcat, biascat, projw_bf, attpw_bf);
  if (pathA)
    convert_x<<<2048, 256, 0, stream>>>((const float4*)cmn, (ushort4*)x_bf, 61440000 / 4);

  for (int t = 0; t < 20; ++t) {
    const ushort_t *a1f, *a1b;
    int lda1;
    if (pathA) {
      a1f = x_bf + (size_t)t * 768;
      a1b = x_bf + (size_t)(19 - t) * 768;
      lda1 = 15360;
    } else {
      convert_slice<<<2048, 256, 0, stream>>>(cmn, xslice, t);
      a1f = xslice;
      a1b = xslice + (size_t)4000 * 768;
      lda1 = 768;
    }
    gemm_gates<<<dim3(63, 7, 2), 256, 0, stream>>>(a1f, a1b, lda1, h_bf, wihcat, whhcat, gates);
    lstm_cell<<<3125, 256, 0, stream>>>(gates, biascat, c_st, h_bf, hcat, t == 19 ? 1 : 0);
  }

  // proj: cs = relu(hcat @ projW_bf^T + projb)  [4000][768]
  gemm_bias_act<<<dim3(63, 12), 256, 0, stream>>>(hcat, 256, projw_bf, 256, 4000, 768, 4,
                                                  projb, nullptr, cs, 768);
  rowdot<<<5120, 64, 0, stream>>>(bert, 768, W1w, W1b, part1, 5120);
  rowdot<<<4000, 64, 0, stream>>>(cs, 768, W2w, W2b, part2, 4000);
  bertw3_k<<<1024, 256, 0, stream>>>(bert, W3, bertW3);
  // total[b,s,p] = part1 + part2 + bertW3@cs^T + masks
  bgemm<1, 1><<<dim3(4, 4, 40), dim3(16, 16), 0, stream>>>(
      bertW3, 98304LL, 768, cs, 76800LL, 768, total_s, 12800LL, 100,
      128, 100, 768, part1, part2, amask, cmask);
  softmax_p<<<5120, 64, 0, stream>>>(total_s, cs_att);
  softmax_s<<<4000, 64, 0, stream>>>(total_s, ctx_att);
  // weight_cs = cs_att @ cs
  bgemm<0, 0><<<dim3(24, 4, 40), dim3(16, 16), 0, stream>>>(
      cs_att, 12800LL, 100, cs, 76800LL, 768, wcs, 98304LL, 768,
      128, 768, 100, nullptr, nullptr, nullptr, nullptr);
  // probs = cs_att @ ctx_att^T
  bgemm<1, 0><<<dim3(4, 4, 40), dim3(16, 16), 0, stream>>>(
      cs_att, 12800LL, 100, ctx_att, 12800LL, 100, probs, 16384LL, 128,
      128, 128, 100, nullptr, nullptr, nullptr, nullptr);
  // weighted_context = probs @ bert
  bgemm<0, 0><<<dim3(24, 4, 40), dim3(16, 16), 0, stream>>>(
      probs, 16384LL, 128, bert, 98304LL, 768, wctx, 98304LL, 768,
      128, 768, 128, nullptr, nullptr, nullptr, nullptr);
  catk<<<2048, 256, 0, stream>>>(bert, wcs, wctx, cat);
  // x = relu(cat @ attpW^T + attpb) + bert  -> d_out, then LN in place
  gemm_bias_act<<<dim3(80, 12), 256, 0, stream>>>(cat, 3072, attpw_bf, 3072, 5120, 768, 48,
                                                  attpb, bert, (float*)d_out, 768);
  layernorm<<<5120, 256, 0, stream>>>((float*)d_out, lnw, lnb);
}

// Round 2
// 849.405 us; speedup vs baseline: 1.3427x; 1.3427x over previous
//
#include <hip/hip_runtime.h>

// QANet attention layer on MI355X (gfx950).
// B=40,S=128,H=768, NP=100, PL=20, HID=100, N=4000 sequences.
// Round 2: LSTM restructured: pre = x@Wih^T (one 98 GF MFMA GEMM, m97-style
// 128x128 tile + global_load_lds) then a SINGLE fused recurrence kernel
// (rows independent across time -> no grid sync; Whh resident in LDS).

typedef unsigned short ushort_t;
typedef unsigned int u32;
typedef __attribute__((ext_vector_type(8))) short short8;
typedef __attribute__((ext_vector_type(4))) float f32x4;
typedef __attribute__((address_space(1))) const u32 gu32;
typedef __attribute__((address_space(3))) u32 lu32;

__device__ __forceinline__ ushort_t f2bf(float f) {
  u32 x = __builtin_bit_cast(u32, f);
  u32 r = (x + 0x7fffu + ((x >> 16) & 1u)) >> 16;
  return (ushort_t)r;
}

__device__ __forceinline__ float sigm(float x) { return 1.f / (1.f + __expf(-x)); }
__device__ __forceinline__ float tanh_f(float x) { return 1.f - 2.f / (__expf(2.f * x) + 1.f); }

// ---------------- prep / convert kernels ----------------

__global__ void prep_weights(const float* __restrict__ Wih_f, const float* __restrict__ Wih_b,
                             const float* __restrict__ Whh_f, const float* __restrict__ Whh_b,
                             const float* __restrict__ bih_f, const float* __restrict__ bhh_f,
                             const float* __restrict__ bih_b, const float* __restrict__ bhh_b,
                             const float* __restrict__ projW, const float* __restrict__ attpW,
                             ushort_t* __restrict__ wihcat, ushort_t* __restrict__ whhcat,
                             float* __restrict__ biascat, ushort_t* __restrict__ projw_bf,
                             ushort_t* __restrict__ attpw_bf) {
  const int TOT = 614400 + 102400 + 800 + 196608 + 2359296;
  for (int idx = blockIdx.x * 256 + threadIdx.x; idx < TOT; idx += gridDim.x * 256) {
    if (idx < 614400) {                       // Wih cat [800][768]
      int g = idx / 768, k = idx % 768;
      float v = g < 400 ? Wih_f[g * 768 + k] : Wih_b[(g - 400) * 768 + k];
      wihcat[idx] = f2bf(v);
    } else if (idx < 716800) {                // Whh cat padded [2][400][128]
      int e = idx - 614400; int g = e / 128, j = e % 128;
      float v = 0.f;
      if (j < 100) v = g < 400 ? Whh_f[g * 100 + j] : Whh_b[(g - 400) * 100 + j];
      whhcat[e] = f2bf(v);
    } else if (idx < 717600) {                // bias cat [800]
      int g = idx - 716800;
      biascat[g] = g < 400 ? bih_f[g] + bhh_f[g] : bih_b[g - 400] + bhh_b[g - 400];
    } else if (idx < 914208) {                // projW padded [768][256]
      int e = idx - 717600; int o = e / 256, j = e % 256;
      float v = 0.f;
      if (j < 100) v = projW[o * 200 + j];
      else if (j >= 128 && j < 228) v = projW[o * 200 + 100 + (j - 128)];
      projw_bf[e] = f2bf(v);
    } else {                                  // attpW [768][3072]
      int e = idx - 914208;
      attpw_bf[e] = f2bf(attpW[e]);
    }
  }
}

__global__ void convert_x(const float4* __restrict__ x, ushort4* __restrict__ xb, int n4) {
  for (int i = blockIdx.x * 256 + threadIdx.x; i < n4; i += gridDim.x * 256) {
    float4 v = x[i];
    ushort4 o;
    o.x = f2bf(v.x); o.y = f2bf(v.y); o.z = f2bf(v.z); o.w = f2bf(v.w);
    xb[i] = o;
  }
}

// ---------------- 128x128 MFMA GEMM (m97-style, global_load_lds) ----------------
// C = A(MxK,bf16) * B(NxK,bf16)^T ; BK=64. LDS rows of 64 bf16 = 8x16B slots,
// XOR swizzle slot^(row&7); global source pre-swizzled so linear DMA writes land
// swizzled (both-sides-or-neither rule).
// EPI 0: pre-activation output: +bias, remap row m=(seq*20+t) -> [t][seq], C ld=800
// EPI 1: relu(v+bias)
// EPI 2: relu(v+bias)+resid

template <int EPI>
__global__ __launch_bounds__(256) void gemm128(
    const ushort_t* __restrict__ A, int lda,
    const ushort_t* __restrict__ B, int ldb,
    int M, int N, int KT,
    const float* __restrict__ bias,
    const float* __restrict__ resid,
    float* __restrict__ C, int ldc)
{
  __shared__ __align__(16) ushort_t lsA[128 * 64];
  __shared__ __align__(16) ushort_t lsB[128 * 64];
  int m0 = blockIdx.x * 128, n0 = blockIdx.y * 128;
  int tid = threadIdx.x, lane = tid & 63, w = tid >> 6;
  int wr = w >> 1, wc = w & 1;
  int l15 = lane & 15, lk = lane >> 4;
  f32x4 acc[4][4];
  #pragma unroll
  for (int i = 0; i < 4; ++i)
    #pragma unroll
    for (int j = 0; j < 4; ++j)
      #pragma unroll
      for (int r = 0; r < 4; ++r) acc[i][j][r] = 0.f;

  int r_in = lane >> 3, p = lane & 7;   // staging coords: 8 rows x 8 slots per 1KB segment
  for (int kt = 0; kt < KT; ++kt) {
    __syncthreads();
    #pragma unroll
    for (int i = 0; i < 4; ++i) {
      int seg = w * 4 + i;
      int row = seg * 8 + r_in;
      int sl = p ^ (row & 7);            // inverse-swizzled source slot
      int m = m0 + row;
      if (m < M)
        __builtin_amdgcn_global_load_lds(
            (gu32*)(A + (size_t)m * lda + kt * 64 + sl * 8),
            (lu32*)(lsA + seg * 512), 16, 0, 0);
      int n = n0 + row;
      if (n < N)
        __builtin_amdgcn_global_load_lds(
            (gu32*)(B + (size_t)n * ldb + kt * 64 + sl * 8),
            (lu32*)(lsB + seg * 512), 16, 0, 0);
    }
    __syncthreads();   // drains vmcnt -> LDS ready
    #pragma unroll
    for (int ks = 0; ks < 2; ++ks) {
      short8 af[4], bfv[4];
      #pragma unroll
      for (int f = 0; f < 4; ++f) {
        int row = wr * 64 + f * 16 + l15;
        af[f] = *reinterpret_cast<const short8*>(
            &lsA[row * 64 + (((ks * 4 + lk) ^ (row & 7)) << 3)]);
        int rowb = wc * 64 + f * 16 + l15;
        bfv[f] = *reinterpret_cast<const short8*>(
            &lsB[rowb * 64 + (((ks * 4 + lk) ^ (rowb & 7)) << 3)]);
      }
      #pragma unroll
      for (int fm = 0; fm < 4; ++fm)
        #pragma unroll
        for (int fn = 0; fn < 4; ++fn)
          acc[fm][fn] = __builtin_amdgcn_mfma_f32_16x16x32_bf16(af[fm], bfv[fn], acc[fm][fn], 0, 0, 0);
    }
  }
  #pragma unroll
  for (int fm = 0; fm < 4; ++fm)
    #pragma unroll
    for (int fn = 0; fn < 4; ++fn)
      #pragma unroll
      for (int r = 0; r < 4; ++r) {
        int m = m0 + wr * 64 + fm * 16 + lk * 4 + r;
        int n = n0 + wc * 64 + fn * 16 + l15;
        if (m < M && n < N) {
          float v = acc[fm][fn][r] + bias[n];
          if (EPI == 0) {
            int sq = m / 20, tstep = m - sq * 20;       // m = seq*20 + t
            C[((size_t)tstep * 4000 + sq) * ldc + n] = v;
          } else {
            v = fmaxf(v, 0.f);
            if (EPI == 2) v += resid[(size_t)m * ldc + n];
            C[(size_t)m * ldc + n] = v;
          }
        }
      }
}

// ---------------- fused biLSTM recurrence ----------------
// grid (63, 2): 64 rows x 1 direction per block, 4 waves (16 rows each).
// Whh [400 gatecols][128 k] bf16 in LDS (102.4 KB, swizzled slot^(row&15));
// h [64][128] bf16 in LDS (16 KB). c-state + gates live in registers.
// Per step: acc(25 frags) = h @ Whh^T (MFMA K=128) + pre (global loads, latency
// hidden under MFMA); f/g/o gathered cross-lane (100 = 6*16+4 slot shift) via
// source-side select + one shfl each; cell in f32; h written back to LDS.

__global__ __launch_bounds__(256) void lstm_recur(
    const float* __restrict__ pre,       // [20][4000][800] f32 (bias included)
    const ushort_t* __restrict__ whh,    // [2][400][128] bf16 (k-padded)
    ushort_t* __restrict__ hcat)         // [4000][256] bf16 out
{
  __shared__ __align__(16) ushort_t whh_lds[400 * 128];
  __shared__ __align__(16) ushort_t h_lds[64 * 128];

  int dir = blockIdx.y;
  int rb = blockIdx.x;
  int tid = threadIdx.x;
  int lane = tid & 63, w = tid >> 6;
  int s = lane & 15, lk = lane >> 4;

  // one-time: Whh -> LDS (swizzled), h_lds -> 0 (incl. k-pad cols: must be clean for MFMA)
  const ushort_t* wsrc = whh + (size_t)dir * 400 * 128;
  for (int c = tid; c < 6400; c += 256) {           // 16B chunks: row=c>>4, slot=c&15
    int row = c >> 4, sl = c & 15;
    uint4 v = *reinterpret_cast<const uint4*>(wsrc + row * 128 + sl * 8);
    *reinterpret_cast<uint4*>(&whh_lds[row * 128 + ((sl ^ (row & 15)) << 3)]) = v;
  }
  for (int c = tid; c < 1024; c += 256) {
    uint4 z = {0u, 0u, 0u, 0u};
    *reinterpret_cast<uint4*>(&h_lds[c * 8]) = z;
  }
  __syncthreads();

  float cst[7][4];
  #pragma unroll
  for (int q = 0; q < 7; ++q)
    #pragma unroll
    for (int r = 0; r < 4; ++r) cst[q][r] = 0.f;

  int rowbase = rb * 64 + w * 16;      // wave's global row base

  for (int t = 0; t < 20; ++t) {
    int tt = dir ? (19 - t) : t;
    const float* pb = pre + ((size_t)tt * 4000 + rowbase) * 800 + dir * 400;

    // issue pre loads (consumed after MFMA)
    float pv[25][4];
    #pragma unroll
    for (int q = 0; q < 25; ++q)
      #pragma unroll
      for (int r = 0; r < 4; ++r) {
        int grow = rowbase + lk * 4 + r;
        pv[q][r] = (grow < 4000) ? pb[(size_t)(lk * 4 + r) * 800 + q * 16 + s] : 0.f;
      }

    // acc = h(t-1) @ Whh^T
    f32x4 acc[25];
    #pragma unroll
    for (int q = 0; q < 25; ++q)
      #pragma unroll
      for (int r = 0; r < 4; ++r) acc[q][r] = 0.f;
    #pragma unroll
    for (int ks = 0; ks < 4; ++ks) {
      int arow = w * 16 + s;
      short8 af = *reinterpret_cast<const short8*>(
          &h_lds[arow * 128 + (((ks * 4 + lk) ^ (arow & 15)) << 3)]);
      #pragma unroll
      for (int q = 0; q < 25; ++q) {
        int brow = q * 16 + s;
        short8 bfv = *reinterpret_cast<const short8*>(
            &whh_lds[brow * 128 + (((ks * 4 + lk) ^ (brow & 15)) << 3)]);
        acc[q] = __builtin_amdgcn_mfma_f32_16x16x32_bf16(af, bfv, acc[q], 0, 0, 0);
      }
    }
    #pragma unroll
    for (int q = 0; q < 25; ++q)
      #pragma unroll
      for (int r = 0; r < 4; ++r) acc[q][r] += pv[q][r];

    // cell: i local (frags 0..6); f at +100, g at +200, o at +300 via shfl
    float hreg[7][4];
    #pragma unroll
    for (int q = 0; q < 7; ++q) {
      #pragma unroll
      for (int r = 0; r < 4; ++r) {
        // source-side frag select, then pull
        float tf_s = (s >= 4)  ? acc[q + 6][r]  : acc[q + 7][r];
        float tg_s = (s >= 8)  ? acc[q + 12][r] : acc[q + 13][r];
        float to_s = (s >= 12) ? acc[q + 18][r] : acc[(q + 19 <= 24) ? (q + 19) : 0][r];
        float fv = __shfl(tf_s, (lane & 48) | ((s + 4) & 15));
        float gv = __shfl(tg_s, (lane & 48) | ((s + 8) & 15));
        float ov = __shfl(to_s, (lane & 48) | ((s + 12) & 15));
        float iv = acc[q][r];
        float c = sigm(fv) * cst[q][r] + sigm(iv) * tanh_f(gv);
        cst[q][r] = c;
        hreg[q][r] = sigm(ov) * tanh_f(c);
      }
    }
    __syncthreads();   // all waves done reading h_lds
    #pragma unroll
    for (int q = 0; q < 7; ++q) {
      int j = q * 16 + s;
      if (j < 100) {
        #pragma unroll
        for (int r = 0; r < 4; ++r) {
          int lr = w * 16 + lk * 4 + r;
          h_lds[lr * 128 + (((j >> 3) ^ (lr & 15)) << 3) + (j & 7)] = f2bf(hreg[q][r]);
        }
      }
    }
    __syncthreads();   // writes visible before next step's MFMA
  }

  // final h -> hcat[n][dir*128 .. +127] (pad cols are zeros from h_lds init)
  for (int c = tid; c < 1024; c += 256) {
    int row = c >> 4, sl = c & 15;
    int g = rb * 64 + row;
    if (g < 4000) {
      uint4 v = *reinterpret_cast<const uint4*>(&h_lds[row * 128 + ((sl ^ (row & 15)) << 3)]);
      *reinterpret_cast<uint4*>(&hcat[(size_t)g * 256 + dir * 128 + sl * 8]) = v;
    }
  }
}

// ---------------- small f32 kernels (unchanged) ----------------

__global__ void rowdot(const float* __restrict__ X, int ld, const float* __restrict__ w,
                       const float* __restrict__ b0, float* __restrict__ out, int nrows) {
  int row = blockIdx.x;
  if (row >= nrows) return;
  int lane = threadIdx.x;   // 64
  const float* x = X + (size_t)row * ld;
  float s = 0.f;
  for (int k = lane; k < 768; k += 64) s += x[k] * w[k];
  for (int off = 32; off; off >>= 1) s += __shfl_down(s, off);
  if (lane == 0) out[row] = s + b0[0];
}

__global__ void bertw3_k(const float* __restrict__ bert, const float* __restrict__ W3,
                         float* __restrict__ out) {
  const int TOT = 40 * 128 * 768;
  for (int i = blockIdx.x * 256 + threadIdx.x; i < TOT; i += gridDim.x * 256)
    out[i] = bert[i] * W3[i % 768];
}

template <int TRANSB, int EPI>
__global__ __launch_bounds__(256) void bgemm(
    const float* __restrict__ A, long long sA, int lda,
    const float* __restrict__ B, long long sB, int ldb,
    float* __restrict__ C, long long sC, int ldc,
    int M, int N, int K,
    const float* __restrict__ p1, const float* __restrict__ p2,
    const int* __restrict__ amask, const int* __restrict__ cmask) {
  int b = blockIdx.z;
  __shared__ float As[32][33], Bs[32][33];
  int tx = threadIdx.x, ty = threadIdx.y;
  int t = ty * 16 + tx;
  int n0 = blockIdx.x * 32, m0 = blockIdx.y * 32;
  const float* Ab = A + (size_t)b * sA;
  const float* Bb = B + (size_t)b * sB;
  float c00 = 0, c01 = 0, c10 = 0, c11 = 0;
  for (int k0 = 0; k0 < K; k0 += 32) {
    __syncthreads();
    #pragma unroll
    for (int i = 0; i < 4; ++i) {
      int e = t + i * 256;
      int r = e >> 5, q = e & 31;
      {
        int m = m0 + r, k = k0 + q;
        As[r][q] = (m < M && k < K) ? Ab[(size_t)m * lda + k] : 0.f;
      }
      if (TRANSB) {
        int n = n0 + r, k = k0 + q;
        Bs[q][r] = (n < N && k < K) ? Bb[(size_t)n * ldb + k] : 0.f;
      } else {
        int k = k0 + r, n = n0 + q;
        Bs[r][q] = (k < K && n < N) ? Bb[(size_t)k * ldb + n] : 0.f;
      }
    }
    __syncthreads();
    #pragma unroll 8
    for (int k = 0; k < 32; ++k) {
      float a0 = As[ty][k], a1 = As[ty + 16][k];
      float b0 = Bs[k][tx], b1 = Bs[k][tx + 16];
      c00 += a0 * b0; c01 += a0 * b1;
      c10 += a1 * b0; c11 += a1 * b1;
    }
  }
  float cc[2][2] = {{c00, c01}, {c10, c11}};
  #pragma unroll
  for (int i = 0; i < 2; ++i)
    #pragma unroll
    for (int j = 0; j < 2; ++j) {
      int m = m0 + ty + 16 * i, n = n0 + tx + 16 * j;
      if (m < M && n < N) {
        float v = cc[i][j];
        if (EPI == 1) {
          v += p1[b * M + m] + p2[b * N + n];
          v += (1.f - (float)amask[b * M + m]) * -10000.f;
          v += (1.f - (float)cmask[b * N + n]) * -10000.f;
        }
        C[(size_t)b * sC + (size_t)m * ldc + n] = v;
      }
    }
}

__global__ void softmax_p(const float* __restrict__ total, float* __restrict__ out) {
  int row = blockIdx.x;   // 5120
  int lane = threadIdx.x; // 64
  const float* x = total + (size_t)row * 100;
  float e0 = x[lane];
  bool has1 = (lane + 64) < 100;
  float e1 = has1 ? x[lane + 64] : -3.4e38f;
  float m = fmaxf(e0, e1);
  for (int off = 32; off; off >>= 1) m = fmaxf(m, __shfl_xor(m, off));
  float s0 = expf(e0 - m), s1 = has1 ? expf(e1 - m) : 0.f;
  float s = s0 + s1;
  for (int off = 32; off; off >>= 1) s += __shfl_xor(s, off);
  float inv = 1.f / s;
  float* o = out + (size_t)row * 100;
  o[lane] = s0 * inv;
  if (has1) o[lane + 64] = s1 * inv;
}

__global__ void softmax_s(const float* __restrict__ total, float* __restrict__ out) {
  int col = blockIdx.x;   // 4000
  int b = col / 100, p = col - b * 100;
  int lane = threadIdx.x;
  const float* base = total + (size_t)b * 12800 + p;
  float e0 = base[lane * 100], e1 = base[(lane + 64) * 100];
  float m = fmaxf(e0, e1);
  for (int off = 32; off; off >>= 1) m = fmaxf(m, __shfl_xor(m, off));
  float s0 = expf(e0 - m), s1 = expf(e1 - m);
  float s = s0 + s1;
  for (int off = 32; off; off >>= 1) s += __shfl_xor(s, off);
  float inv = 1.f / s;
  float* o = out + (size_t)b * 12800 + p;
  o[lane * 100] = s0 * inv;
  o[(lane + 64) * 100] = s1 * inv;
}

__global__ void catk(const float* __restrict__ bert, const float* __restrict__ wcs,
                     const float* __restrict__ wctx, ushort_t* __restrict__ cat) {
  const int TOT = 5120 * 3072;
  for (int i = blockIdx.x * 256 + threadIdx.x; i < TOT; i += gridDim.x * 256) {
    int row = i / 3072, col = i - row * 3072;
    int seg = col / 768;
    int h = col - seg * 768;
    size_t e = (size_t)row * 768 + h;
    float v;
    if (seg == 0) v = bert[e];
    else if (seg == 1) v = wcs[e];
    else if (seg == 2) v = bert[e] * wcs[e];
    else v = bert[e] * wctx[e];
    cat[i] = f2bf(v);
  }
}

__global__ __launch_bounds__(256) void layernorm(float* __restrict__ X,
                                                 const float* __restrict__ w,
                                                 const float* __restrict__ bta) {
  int row = blockIdx.x;   // 5120
  float* x = X + (size_t)row * 768;
  int t = threadIdx.x;
  float v[3];
  float s = 0.f;
  #pragma unroll
  for (int i = 0; i < 3; ++i) { v[i] = x[t + 256 * i]; s += v[i]; }
  __shared__ float red[256];
  red[t] = s; __syncthreads();
  for (int off = 128; off; off >>= 1) { if (t < off) red[t] += red[t + off]; __syncthreads(); }
  float mean = red[0] * (1.f / 768.f);
  __syncthreads();
  float q = 0.f;
  #pragma unroll
  for (int i = 0; i < 3; ++i) { float d = v[i] - mean; q += d * d; }
  red[t] = q; __syncthreads();
  for (int off = 128; off; off >>= 1) { if (t < off) red[t] += red[t + off]; __syncthreads(); }
  float inv = rsqrtf(red[0] * (1.f / 768.f) + 1e-12f);
  #pragma unroll
  for (int i = 0; i < 3; ++i) {
    int k = t + 256 * i;
    x[k] = w[k] * ((v[i] - mean) * inv) + bta[k];
  }
}

// ---------------- host orchestration ----------------

extern "C" void kernel_launch(void* const* d_in, const int* in_sizes, int n_in,
                              void* d_out, int out_size, void* d_ws, size_t ws_size,
                              hipStream_t stream) {
  (void)in_sizes; (void)n_in; (void)out_size; (void)ws_size;
  const float* bert  = (const float*)d_in[0];
  const float* cmn   = (const float*)d_in[1];
  const int*   amask = (const int*)d_in[2];
  const int*   cmask = (const int*)d_in[3];
  const float* Wih_f = (const float*)d_in[8];
  const float* Whh_f = (const float*)d_in[9];
  const float* bih_f = (const float*)d_in[10];
  const float* bhh_f = (const float*)d_in[11];
  const float* Wih_b = (const float*)d_in[12];
  const float* Whh_b = (const float*)d_in[13];
  const float* bih_b = (const float*)d_in[14];
  const float* bhh_b = (const float*)d_in[15];
  const float* projW = (const float*)d_in[16];
  const float* projb = (const float*)d_in[17];
  const float* W1w   = (const float*)d_in[18];
  const float* W1b   = (const float*)d_in[19];
  const float* W2w   = (const float*)d_in[20];
  const float* W2b   = (const float*)d_in[21];
  const float* W3    = (const float*)d_in[22];
  const float* attpW = (const float*)d_in[23];
  const float* attpb = (const float*)d_in[24];
  const float* lnw   = (const float*)d_in[25];
  const float* lnb   = (const float*)d_in[26];

  char* base = (char*)d_ws;
  size_t off = 0;
  auto alloc = [&](size_t bytes) -> char* {
    char* r = base + off;
    off += (bytes + 255) & ~(size_t)255;
    return r;
  };
  ushort_t* wihcat   = (ushort_t*)alloc(800 * 768 * 2);
  ushort_t* whhcat   = (ushort_t*)alloc(800 * 128 * 2);
  float*    biascat  = (float*)alloc(800 * 4);
  ushort_t* projw_bf = (ushort_t*)alloc(768 * 256 * 2);
  ushort_t* attpw_bf = (ushort_t*)alloc(768 * 3072 * 2);
  ushort_t* hcat     = (ushort_t*)alloc(4000 * 256 * 2);
  float*    cs       = (float*)alloc((size_t)4000 * 768 * 4);
  float*    part1    = (float*)alloc(5120 * 4);
  float*    part2    = (float*)alloc(4000 * 4);
  float*    total_s  = (float*)alloc((size_t)40 * 128 * 100 * 4);
  float*    cs_att   = (float*)alloc((size_t)40 * 128 * 100 * 4);
  float*    ctx_att  = (float*)alloc((size_t)40 * 128 * 100 * 4);
  float*    bertW3   = (float*)alloc((size_t)40 * 128 * 768 * 4);
  float*    probs    = (float*)alloc((size_t)40 * 128 * 128 * 4);
  float*    wcs      = (float*)alloc((size_t)40 * 128 * 768 * 4);
  float*    wctx     = (float*)alloc((size_t)40 * 128 * 768 * 4);
  ushort_t* cat      = (ushort_t*)alloc((size_t)5120 * 3072 * 2);
  ushort_t* x_bf     = (ushort_t*)alloc((size_t)4000 * 20 * 768 * 2);   // 123 MB
  float*    pre      = (float*)alloc((size_t)20 * 4000 * 800 * 4);      // 256 MB

  prep_weights<<<512, 256, 0, stream>>>(Wih_f, Wih_b, Whh_f, Whh_b, bih_f, bhh_f, bih_b, bhh_b,
                                        projW, attpW, wihcat, whhcat, biascat, projw_bf, attpw_bf);
  convert_x<<<2048, 256, 0, stream>>>((const float4*)cmn, (ushort4*)x_bf, 61440000 / 4);

  // pre[t][n][g] = x @ Wih^T + (bih+bhh)   (M=80000, N=800, K=768)
  gemm128<0><<<dim3(625, 7), 256, 0, stream>>>(x_bf, 768, wihcat, 768, 80000, 800, 12,
                                               biascat, nullptr, pre, 800);
  // fused 20-step bidirectional recurrence
  lstm_recur<<<dim3(63, 2), 256, 0, stream>>>(pre, whhcat, hcat);

  // cs = relu(hcat @ projW^T + projb)  [4000][768]
  gemm128<1><<<dim3(32, 6), 256, 0, stream>>>(hcat, 256, projw_bf, 256, 4000, 768, 4,
                                              projb, nullptr, cs, 768);
  rowdot<<<5120, 64, 0, stream>>>(bert, 768, W1w, W1b, part1, 5120);
  rowdot<<<4000, 64, 0, stream>>>(cs, 768, W2w, W2b, part2, 4000);
  bertw3_k<<<1024, 256, 0, stream>>>(bert, W3, bertW3);
  // total[b,s,p] = part1 + part2 + bertW3@cs^T + masks
  bgemm<1, 1><<<dim3(4, 4, 40), dim3(16, 16), 0, stream>>>(
      bertW3, 98304LL, 768, cs, 76800LL, 768, total_s, 12800LL, 100,
      128, 100, 768, part1, part2, amask, cmask);
  softmax_p<<<5120, 64, 0, stream>>>(total_s, cs_att);
  softmax_s<<<4000, 64, 0, stream>>>(total_s, ctx_att);
  // weight_cs = cs_att @ cs
  bgemm<0, 0><<<dim3(24, 4, 40), dim3(16, 16), 0, stream>>>(
      cs_att, 12800LL, 100, cs, 76800LL, 768, wcs, 98304LL, 768,
      128, 768, 100, nullptr, nullptr, nullptr, nullptr);
  // probs = cs_att @ ctx_att^T
  bgemm<1, 0><<<dim3(4, 4, 40), dim3(16, 16), 0, stream>>>(
      cs_att, 12800LL, 100, ctx_att, 12800LL, 100, probs, 16384LL, 128,
      128, 128, 100, nullptr, nullptr, nullptr, nullptr);
  // weighted_context = probs @ bert
  bgemm<0, 0><<<dim3(24, 4, 40), dim3(16, 16), 0, stream>>>(
      probs, 16384LL, 128, bert, 98304LL, 768, wctx, 98304LL, 768,
      128, 768, 128, nullptr, nullptr, nullptr, nullptr);
  catk<<<2048, 256, 0, stream>>>(bert, wcs, wctx, cat);
  // x = relu(cat @ attpW^T + attpb) + bert  -> d_out, then LN in place
  gemm128<2><<<dim3(40, 6), 256, 0, stream>>>(cat, 3072, attpw_bf, 3072, 5120, 768, 48,
                                              attpb, bert, (float*)d_out, 768);
  layernorm<<<5120, 256, 0, stream>>>((float*)d_out, lnw, lnb);
}

// Round 3
// 673.930 us; speedup vs baseline: 1.6923x; 1.2604x over previous
//
#include <hip/hip_runtime.h>

// QANet attention layer on MI355X (gfx950).
// B=40,S=128,H=768, NP=100, PL=20, HID=100, N=4000 sequences.
// Round 3: lane-matched bf16 `pre` layout [20][250][50][256] (off=s*16+lk*4+r
// == MFMA C/D map), t-major x, recurrence rewritten: 16-row blocks (500 blocks),
// Whh in VGPRs (q-partition per wave), LDS gate-exchange, reg-dbuf pre prefetch.

typedef unsigned short ushort_t;
typedef unsigned int u32;
typedef __attribute__((ext_vector_type(8))) short short8;
typedef __attribute__((ext_vector_type(4))) float f32x4;
typedef __attribute__((address_space(1))) const u32 gu32;
typedef __attribute__((address_space(3))) u32 lu32;

__device__ __forceinline__ ushort_t f2bf(float f) {
  u32 x = __builtin_bit_cast(u32, f);
  u32 r = (x + 0x7fffu + ((x >> 16) & 1u)) >> 16;
  return (ushort_t)r;
}
__device__ __forceinline__ float bflo(u32 u) { return __builtin_bit_cast(float, u << 16); }
__device__ __forceinline__ float bfhi(u32 u) { return __builtin_bit_cast(float, u & 0xffff0000u); }

__device__ __forceinline__ float sigm(float x) { return 1.f / (1.f + __expf(-x)); }
__device__ __forceinline__ float tanh_f(float x) { return 1.f - 2.f / (__expf(2.f * x) + 1.f); }

// ---------------- prep / convert kernels ----------------

__global__ void prep_weights(const float* __restrict__ Wih_f, const float* __restrict__ Wih_b,
                             const float* __restrict__ Whh_f, const float* __restrict__ Whh_b,
                             const float* __restrict__ bih_f, const float* __restrict__ bhh_f,
                             const float* __restrict__ bih_b, const float* __restrict__ bhh_b,
                             const float* __restrict__ projW, const float* __restrict__ attpW,
                             ushort_t* __restrict__ wihcat, ushort_t* __restrict__ whhcat,
                             float* __restrict__ biascat, ushort_t* __restrict__ projw_bf,
                             ushort_t* __restrict__ attpw_bf) {
  const int TOT = 614400 + 102400 + 800 + 196608 + 2359296;
  for (int idx = blockIdx.x * 256 + threadIdx.x; idx < TOT; idx += gridDim.x * 256) {
    if (idx < 614400) {                       // Wih cat [800][768]
      int g = idx / 768, k = idx % 768;
      float v = g < 400 ? Wih_f[g * 768 + k] : Wih_b[(g - 400) * 768 + k];
      wihcat[idx] = f2bf(v);
    } else if (idx < 716800) {                // Whh cat padded [2][400][128]
      int e = idx - 614400; int g = e / 128, j = e % 128;
      float v = 0.f;
      if (j < 100) v = g < 400 ? Whh_f[g * 100 + j] : Whh_b[(g - 400) * 100 + j];
      whhcat[e] = f2bf(v);
    } else if (idx < 717600) {                // bias cat [800]
      int g = idx - 716800;
      biascat[g] = g < 400 ? bih_f[g] + bhh_f[g] : bih_b[g - 400] + bhh_b[g - 400];
    } else if (idx < 914208) {                // projW padded [768][256]
      int e = idx - 717600; int o = e / 256, j = e % 256;
      float v = 0.f;
      if (j < 100) v = projW[o * 200 + j];
      else if (j >= 128 && j < 228) v = projW[o * 200 + 100 + (j - 128)];
      projw_bf[e] = f2bf(v);
    } else {                                  // attpW [768][3072]
      int e = idx - 914208;
      attpw_bf[e] = f2bf(attpW[e]);
    }
  }
}

// x [4000][20][768] f32 -> x_bf [20][4000][768] bf16 (t-major)
__global__ void convert_x_t(const float4* __restrict__ x4, ushort_t* __restrict__ xb) {
  for (int i = blockIdx.x * 256 + threadIdx.x; i < 15360000; i += gridDim.x * 256) {
    int seq = i / 3840;              // 20*192 float4 per seq
    int rem = i - seq * 3840;
    int t = rem / 192;
    int k4 = rem - t * 192;
    float4 v = x4[i];
    ushort4 o;
    o.x = f2bf(v.x); o.y = f2bf(v.y); o.z = f2bf(v.z); o.w = f2bf(v.w);
    *reinterpret_cast<ushort4*>(&xb[((size_t)t * 4000 + seq) * 768 + k4 * 4]) = o;
  }
}

// ---------------- 128x128 MFMA GEMM (m97-style, global_load_lds) ----------------
// C = A(MxK,bf16) * B(NxK,bf16)^T ; BK=64.
// EPI 0: pre-layout store: P[t][seqchunk][nq][off] bf16, off = s*16+lk*4+r (+bias)
// EPI 1: relu(v+bias) f32 out
// EPI 2: relu(v+bias)+resid f32 out

template <int EPI>
__global__ __launch_bounds__(256) void gemm128(
    const ushort_t* __restrict__ A, int lda,
    const ushort_t* __restrict__ B, int ldb,
    int M, int N, int KT,
    const float* __restrict__ bias,
    const float* __restrict__ resid,
    float* __restrict__ C, int ldc)
{
  __shared__ __align__(16) ushort_t lsA[128 * 64];
  __shared__ __align__(16) ushort_t lsB[128 * 64];
  int m0 = blockIdx.x * 128, n0 = blockIdx.y * 128;
  int tid = threadIdx.x, lane = tid & 63, w = tid >> 6;
  int wr = w >> 1, wc = w & 1;
  int l15 = lane & 15, lk = lane >> 4;
  f32x4 acc[4][4];
  #pragma unroll
  for (int i = 0; i < 4; ++i)
    #pragma unroll
    for (int j = 0; j < 4; ++j)
      #pragma unroll
      for (int r = 0; r < 4; ++r) acc[i][j][r] = 0.f;

  int r_in = lane >> 3, p = lane & 7;
  for (int kt = 0; kt < KT; ++kt) {
    __syncthreads();
    #pragma unroll
    for (int i = 0; i < 4; ++i) {
      int seg = w * 4 + i;
      int row = seg * 8 + r_in;
      int sl = p ^ (row & 7);
      int m = m0 + row;
      if (m < M)
        __builtin_amdgcn_global_load_lds(
            (gu32*)(A + (size_t)m * lda + kt * 64 + sl * 8),
            (lu32*)(lsA + seg * 512), 16, 0, 0);
      int n = n0 + row;
      if (n < N)
        __builtin_amdgcn_global_load_lds(
            (gu32*)(B + (size_t)n * ldb + kt * 64 + sl * 8),
            (lu32*)(lsB + seg * 512), 16, 0, 0);
    }
    __syncthreads();
    #pragma unroll
    for (int ks = 0; ks < 2; ++ks) {
      short8 af[4], bfv[4];
      #pragma unroll
      for (int f = 0; f < 4; ++f) {
        int row = wr * 64 + f * 16 + l15;
        af[f] = *reinterpret_cast<const short8*>(
            &lsA[row * 64 + (((ks * 4 + lk) ^ (row & 7)) << 3)]);
        int rowb = wc * 64 + f * 16 + l15;
        bfv[f] = *reinterpret_cast<const short8*>(
            &lsB[rowb * 64 + (((ks * 4 + lk) ^ (rowb & 7)) << 3)]);
      }
      #pragma unroll
      for (int fm = 0; fm < 4; ++fm)
        #pragma unroll
        for (int fn = 0; fn < 4; ++fn)
          acc[fm][fn] = __builtin_amdgcn_mfma_f32_16x16x32_bf16(af[fm], bfv[fn], acc[fm][fn], 0, 0, 0);
    }
  }
  if (EPI == 0) {
    // m = t*4000 + seq (t-major). 16-row fragments never straddle t (4000%16==0).
    ushort_t* P = (ushort_t*)C;
    #pragma unroll
    for (int fm = 0; fm < 4; ++fm) {
      int mb = m0 + wr * 64 + fm * 16;
      if (mb < M) {
        int t = mb / 4000;
        int sq = mb - t * 4000;
        int cch = sq >> 4;
        #pragma unroll
        for (int fn = 0; fn < 4; ++fn) {
          int nb = n0 + wc * 64 + fn * 16;
          if (nb < N) {
            int nl = nb < 400 ? nb : nb - 400;
            int nq = (nb < 400 ? 0 : 25) + (nl >> 4);
            float bsv = bias[nb + l15];
            ushort4 pk;
            pk.x = f2bf(acc[fm][fn][0] + bsv);
            pk.y = f2bf(acc[fm][fn][1] + bsv);
            pk.z = f2bf(acc[fm][fn][2] + bsv);
            pk.w = f2bf(acc[fm][fn][3] + bsv);
            *reinterpret_cast<ushort4*>(
                &P[((((size_t)t * 250 + cch) * 50 + nq) << 8) + l15 * 16 + lk * 4]) = pk;
          }
        }
      }
    }
  } else {
    #pragma unroll
    for (int fm = 0; fm < 4; ++fm)
      #pragma unroll
      for (int fn = 0; fn < 4; ++fn)
        #pragma unroll
        for (int r = 0; r < 4; ++r) {
          int m = m0 + wr * 64 + fm * 16 + lk * 4 + r;
          int n = n0 + wc * 64 + fn * 16 + l15;
          if (m < M && n < N) {
            float v = acc[fm][fn][r] + bias[n];
            v = fmaxf(v, 0.f);
            if (EPI == 2) v += resid[(size_t)m * ldc + n];
            C[(size_t)m * ldc + n] = v;
          }
        }
  }
}

// ---------------- fused biLSTM recurrence v3 ----------------
// grid (250, 2): 16 seqs x 1 dir per block, 4 waves.
// Whh in VGPRs: wave w owns gate-frags q in {w, w+4, ...} (<25).
// Per step: MFMA h@Whh^T (K=128) + pre (reg-prefetched) -> gate-exchange LDS
// (bf16, off-layout) -> cell partitioned by i-frag -> h to LDS (swizzled).

__global__ __launch_bounds__(256) void lstm_recur(
    const ushort_t* __restrict__ pre,    // [20][250][50][256] bf16
    const ushort_t* __restrict__ whh,    // [2][400][128] bf16 (k-padded)
    ushort_t* __restrict__ hcat)         // [4000][256] bf16
{
  __shared__ __align__(16) ushort_t gx[25 * 256];     // gate exchange
  __shared__ __align__(16) ushort_t h_lds[16 * 128];  // h, swizzled slot^row

  int dir = blockIdx.y;
  int c = blockIdx.x;                   // seq chunk (16 seqs)
  int tid = threadIdx.x, lane = tid & 63, w = tid >> 6;
  int s = lane & 15, lk = lane >> 4;

  // Whh fragments -> registers (wave q-partition, stride 4)
  short8 wf[7][4];
  #pragma unroll
  for (int qi = 0; qi < 7; ++qi) {
    int q = w + qi * 4;
    if (q < 25) {
      const ushort_t* wp = whh + ((size_t)dir * 400 + q * 16 + s) * 128;
      #pragma unroll
      for (int ks = 0; ks < 4; ++ks)
        wf[qi][ks] = *reinterpret_cast<const short8*>(wp + ks * 32 + lk * 8);
    }
  }
  // h = 0 (incl. k-pad cols)
  for (int e = tid; e < 1024; e += 256)
    *reinterpret_cast<u32*>(&h_lds[e * 2]) = 0u;

  float cst[2][4];
  #pragma unroll
  for (int g = 0; g < 2; ++g)
    #pragma unroll
    for (int r = 0; r < 4; ++r) cst[g][r] = 0.f;

  uint2 pvA[7], pvB[7];
  {
    int tt0 = dir ? 19 : 0;
    const ushort_t* pb = pre + ((((size_t)tt0 * 250 + c) * 50 + dir * 25) << 8);
    #pragma unroll
    for (int qi = 0; qi < 7; ++qi) {
      int q = w + qi * 4;
      if (q < 25) pvA[qi] = *reinterpret_cast<const uint2*>(pb + (q << 8) + s * 16 + lk * 4);
    }
  }
  __syncthreads();

  auto step = [&](uint2 (&pvc)[7], uint2 (&pvn)[7], int t) {
    // MFMA: acc = h @ Whh^T
    f32x4 acc[7];
    #pragma unroll
    for (int qi = 0; qi < 7; ++qi)
      #pragma unroll
      for (int r = 0; r < 4; ++r) acc[qi][r] = 0.f;
    #pragma unroll
    for (int ks = 0; ks < 4; ++ks) {
      short8 af = *reinterpret_cast<const short8*>(
          &h_lds[s * 128 + (((ks * 4 + lk) ^ s) << 3)]);
      #pragma unroll
      for (int qi = 0; qi < 7; ++qi)
        if (w + qi * 4 < 25)
          acc[qi] = __builtin_amdgcn_mfma_f32_16x16x32_bf16(af, wf[qi][ks], acc[qi], 0, 0, 0);
    }
    // + pre (from prefetch regs)
    #pragma unroll
    for (int qi = 0; qi < 7; ++qi)
      if (w + qi * 4 < 25) {
        acc[qi][0] += bflo(pvc[qi].x); acc[qi][1] += bfhi(pvc[qi].x);
        acc[qi][2] += bflo(pvc[qi].y); acc[qi][3] += bfhi(pvc[qi].y);
      }
    // prefetch next step's pre
    if (t + 1 < 20) {
      int tn = dir ? 19 - (t + 1) : (t + 1);
      const ushort_t* pb = pre + ((((size_t)tn * 250 + c) * 50 + dir * 25) << 8);
      #pragma unroll
      for (int qi = 0; qi < 7; ++qi) {
        int q = w + qi * 4;
        if (q < 25) pvn[qi] = *reinterpret_cast<const uint2*>(pb + (q << 8) + s * 16 + lk * 4);
      }
    }
    // gate preacts -> exchange LDS (bf16, coalesced 8B stores)
    #pragma unroll
    for (int qi = 0; qi < 7; ++qi) {
      int q = w + qi * 4;
      if (q < 25) {
        ushort4 pk;
        pk.x = f2bf(acc[qi][0]); pk.y = f2bf(acc[qi][1]);
        pk.z = f2bf(acc[qi][2]); pk.w = f2bf(acc[qi][3]);
        *reinterpret_cast<ushort4*>(&gx[(q << 8) + s * 16 + lk * 4]) = pk;
      }
    }
    __syncthreads();
    // cell: wave handles i-frags gi where gi%4==w
    #pragma unroll
    for (int gd = 0; gd < 2; ++gd) {
      int gi = w + gd * 4;
      if (gi < 7) {
        int j = gi * 16 + s;
        if (j < 100) {
          auto ld2 = [&](int q, int sp) {
            return *reinterpret_cast<const uint2*>(&gx[(q << 8) + sp * 16 + lk * 4]);
          };
          uint2 iv = ld2(gi, s);
          uint2 fv = (s < 12) ? ld2(6 + gi, s + 4) : ld2(7 + gi, s - 12);
          uint2 gv = (s < 8) ? ld2(12 + gi, s + 8) : ld2(13 + gi, s - 8);
          uint2 ov = (s < 4) ? ld2(18 + gi, s + 12) : ld2(19 + gi, s - 4);
          float ia[4] = {bflo(iv.x), bfhi(iv.x), bflo(iv.y), bfhi(iv.y)};
          float fa[4] = {bflo(fv.x), bfhi(fv.x), bflo(fv.y), bfhi(fv.y)};
          float ga[4] = {bflo(gv.x), bfhi(gv.x), bflo(gv.y), bfhi(gv.y)};
          float oa[4] = {bflo(ov.x), bfhi(ov.x), bflo(ov.y), bfhi(ov.y)};
          #pragma unroll
          for (int r = 0; r < 4; ++r) {
            float cc = sigm(fa[r]) * cst[gd][r] + sigm(ia[r]) * tanh_f(ga[r]);
            cst[gd][r] = cc;
            int row = lk * 4 + r;
            h_lds[row * 128 + (((j >> 3) ^ row) << 3) + (j & 7)] =
                f2bf(sigm(oa[r]) * tanh_f(cc));
          }
        }
      }
    }
    __syncthreads();
  };

  #pragma unroll 1
  for (int tp = 0; tp < 10; ++tp) {
    step(pvA, pvB, 2 * tp);
    step(pvB, pvA, 2 * tp + 1);
  }

  // final h -> hcat (un-swizzle); pad cols 100..127 are zeros from init
  {
    int row = tid >> 4, sl = tid & 15;
    uint2 v = *reinterpret_cast<const uint2*>(&h_lds[row * 128 + ((sl ^ row) << 3)]);
    *reinterpret_cast<uint2*>(&hcat[(size_t)(c * 16 + row) * 256 + dir * 128 + sl * 8]) = v;
  }
}

// ---------------- small f32 kernels ----------------

__global__ void rowdot(const float* __restrict__ X, int ld, const float* __restrict__ w,
                       const float* __restrict__ b0, float* __restrict__ out, int nrows) {
  int row = blockIdx.x;
  if (row >= nrows) return;
  int lane = threadIdx.x;   // 64
  const float* x = X + (size_t)row * ld;
  float s = 0.f;
  for (int k = lane; k < 768; k += 64) s += x[k] * w[k];
  for (int off = 32; off; off >>= 1) s += __shfl_down(s, off);
  if (lane == 0) out[row] = s + b0[0];
}

__global__ void bertw3_k(const float* __restrict__ bert, const float* __restrict__ W3,
                         float* __restrict__ out) {
  const int TOT = 40 * 128 * 768;
  for (int i = blockIdx.x * 256 + threadIdx.x; i < TOT; i += gridDim.x * 256)
    out[i] = bert[i] * W3[i % 768];
}

template <int TRANSB, int EPI>
__global__ __launch_bounds__(256) void bgemm(
    const float* __restrict__ A, long long sA, int lda,
    const float* __restrict__ B, long long sB, int ldb,
    float* __restrict__ C, long long sC, int ldc,
    int M, int N, int K,
    const float* __restrict__ p1, const float* __restrict__ p2,
    const int* __restrict__ amask, const int* __restrict__ cmask) {
  int b = blockIdx.z;
  __shared__ float As[32][33], Bs[32][33];
  int tx = threadIdx.x, ty = threadIdx.y;
  int t = ty * 16 + tx;
  int n0 = blockIdx.x * 32, m0 = blockIdx.y * 32;
  const float* Ab = A + (size_t)b * sA;
  const float* Bb = B + (size_t)b * sB;
  float c00 = 0, c01 = 0, c10 = 0, c11 = 0;
  for (int k0 = 0; k0 < K; k0 += 32) {
    __syncthreads();
    #pragma unroll
    for (int i = 0; i < 4; ++i) {
      int e = t + i * 256;
      int r = e >> 5, q = e & 31;
      {
        int m = m0 + r, k = k0 + q;
        As[r][q] = (m < M && k < K) ? Ab[(size_t)m * lda + k] : 0.f;
      }
      if (TRANSB) {
        int n = n0 + r, k = k0 + q;
        Bs[q][r] = (n < N && k < K) ? Bb[(size_t)n * ldb + k] : 0.f;
      } else {
        int k = k0 + r, n = n0 + q;
        Bs[r][q] = (k < K && n < N) ? Bb[(size_t)k * ldb + n] : 0.f;
      }
    }
    __syncthreads();
    #pragma unroll 8
    for (int k = 0; k < 32; ++k) {
      float a0 = As[ty][k], a1 = As[ty + 16][k];
      float b0 = Bs[k][tx], b1 = Bs[k][tx + 16];
      c00 += a0 * b0; c01 += a0 * b1;
      c10 += a1 * b0; c11 += a1 * b1;
    }
  }
  float cc[2][2] = {{c00, c01}, {c10, c11}};
  #pragma unroll
  for (int i = 0; i < 2; ++i)
    #pragma unroll
    for (int j = 0; j < 2; ++j) {
      int m = m0 + ty + 16 * i, n = n0 + tx + 16 * j;
      if (m < M && n < N) {
        float v = cc[i][j];
        if (EPI == 1) {
          v += p1[b * M + m] + p2[b * N + n];
          v += (1.f - (float)amask[b * M + m]) * -10000.f;
          v += (1.f - (float)cmask[b * N + n]) * -10000.f;
        }
        C[(size_t)b * sC + (size_t)m * ldc + n] = v;
      }
    }
}

__global__ void softmax_p(const float* __restrict__ total, float* __restrict__ out) {
  int row = blockIdx.x;   // 5120
  int lane = threadIdx.x; // 64
  const float* x = total + (size_t)row * 100;
  float e0 = x[lane];
  bool has1 = (lane + 64) < 100;
  float e1 = has1 ? x[lane + 64] : -3.4e38f;
  float m = fmaxf(e0, e1);
  for (int off = 32; off; off >>= 1) m = fmaxf(m, __shfl_xor(m, off));
  float s0 = expf(e0 - m), s1 = has1 ? expf(e1 - m) : 0.f;
  float s = s0 + s1;
  for (int off = 32; off; off >>= 1) s += __shfl_xor(s, off);
  float inv = 1.f / s;
  float* o = out + (size_t)row * 100;
  o[lane] = s0 * inv;
  if (has1) o[lane + 64] = s1 * inv;
}

__global__ void softmax_s(const float* __restrict__ total, float* __restrict__ out) {
  int col = blockIdx.x;   // 4000
  int b = col / 100, p = col - b * 100;
  int lane = threadIdx.x;
  const float* base = total + (size_t)b * 12800 + p;
  float e0 = base[lane * 100], e1 = base[(lane + 64) * 100];
  float m = fmaxf(e0, e1);
  for (int off = 32; off; off >>= 1) m = fmaxf(m, __shfl_xor(m, off));
  float s0 = expf(e0 - m), s1 = expf(e1 - m);
  float s = s0 + s1;
  for (int off = 32; off; off >>= 1) s += __shfl_xor(s, off);
  float inv = 1.f / s;
  float* o = out + (size_t)b * 12800 + p;
  o[lane * 100] = s0 * inv;
  o[(lane + 64) * 100] = s1 * inv;
}

__global__ void catk(const float* __restrict__ bert, const float* __restrict__ wcs,
                     const float* __restrict__ wctx, ushort_t* __restrict__ cat) {
  const int TOT = 5120 * 3072;
  for (int i = blockIdx.x * 256 + threadIdx.x; i < TOT; i += gridDim.x * 256) {
    int row = i / 3072, col = i - row * 3072;
    int seg = col / 768;
    int h = col - seg * 768;
    size_t e = (size_t)row * 768 + h;
    float v;
    if (seg == 0) v = bert[e];
    else if (seg == 1) v = wcs[e];
    else if (seg == 2) v = bert[e] * wcs[e];
    else v = bert[e] * wctx[e];
    cat[i] = f2bf(v);
  }
}

__global__ __launch_bounds__(256) void layernorm(float* __restrict__ X,
                                                 const float* __restrict__ w,
                                                 const float* __restrict__ bta) {
  int row = blockIdx.x;   // 5120
  float* x = X + (size_t)row * 768;
  int t = threadIdx.x;
  float v[3];
  float s = 0.f;
  #pragma unroll
  for (int i = 0; i < 3; ++i) { v[i] = x[t + 256 * i]; s += v[i]; }
  __shared__ float red[256];
  red[t] = s; __syncthreads();
  for (int off = 128; off; off >>= 1) { if (t < off) red[t] += red[t + off]; __syncthreads(); }
  float mean = red[0] * (1.f / 768.f);
  __syncthreads();
  float q = 0.f;
  #pragma unroll
  for (int i = 0; i < 3; ++i) { float d = v[i] - mean; q += d * d; }
  red[t] = q; __syncthreads();
  for (int off = 128; off; off >>= 1) { if (t < off) red[t] += red[t + off]; __syncthreads(); }
  float inv = rsqrtf(red[0] * (1.f / 768.f) + 1e-12f);
  #pragma unroll
  for (int i = 0; i < 3; ++i) {
    int k = t + 256 * i;
    x[k] = w[k] * ((v[i] - mean) * inv) + bta[k];
  }
}

// ---------------- host orchestration ----------------

extern "C" void kernel_launch(void* const* d_in, const int* in_sizes, int n_in,
                              void* d_out, int out_size, void* d_ws, size_t ws_size,
                              hipStream_t stream) {
  (void)in_sizes; (void)n_in; (void)out_size; (void)ws_size;
  const float* bert  = (const float*)d_in[0];
  const float* cmn   = (const float*)d_in[1];
  const int*   amask = (const int*)d_in[2];
  const int*   cmask = (const int*)d_in[3];
  const float* Wih_f = (const float*)d_in[8];
  const float* Whh_f = (const float*)d_in[9];
  const float* bih_f = (const float*)d_in[10];
  const float* bhh_f = (const float*)d_in[11];
  const float* Wih_b = (const float*)d_in[12];
  const float* Whh_b = (const float*)d_in[13];
  const float* bih_b = (const float*)d_in[14];
  const float* bhh_b = (const float*)d_in[15];
  const float* projW = (const float*)d_in[16];
  const float* projb = (const float*)d_in[17];
  const float* W1w   = (const float*)d_in[18];
  const float* W1b   = (const float*)d_in[19];
  const float* W2w   = (const float*)d_in[20];
  const float* W2b   = (const float*)d_in[21];
  const float* W3    = (const float*)d_in[22];
  const float* attpW = (const float*)d_in[23];
  const float* attpb = (const float*)d_in[24];
  const float* lnw   = (const float*)d_in[25];
  const float* lnb   = (const float*)d_in[26];

  char* base = (char*)d_ws;
  size_t off = 0;
  auto alloc = [&](size_t bytes) -> char* {
    char* r = base + off;
    off += (bytes + 255) & ~(size_t)255;
    return r;
  };
  ushort_t* wihcat   = (ushort_t*)alloc(800 * 768 * 2);
  ushort_t* whhcat   = (ushort_t*)alloc(800 * 128 * 2);
  float*    biascat  = (float*)alloc(800 * 4);
  ushort_t* projw_bf = (ushort_t*)alloc(768 * 256 * 2);
  ushort_t* attpw_bf = (ushort_t*)alloc(768 * 3072 * 2);
  ushort_t* hcat     = (ushort_t*)alloc(4000 * 256 * 2);
  float*    cs       = (float*)alloc((size_t)4000 * 768 * 4);
  float*    part1    = (float*)alloc(5120 * 4);
  float*    part2    = (float*)alloc(4000 * 4);
  float*    total_s  = (float*)alloc((size_t)40 * 128 * 100 * 4);
  float*    cs_att   = (float*)alloc((size_t)40 * 128 * 100 * 4);
  float*    ctx_att  = (float*)alloc((size_t)40 * 128 * 100 * 4);
  float*    bertW3   = (float*)alloc((size_t)40 * 128 * 768 * 4);
  float*    probs    = (float*)alloc((size_t)40 * 128 * 128 * 4);
  float*    wcs      = (float*)alloc((size_t)40 * 128 * 768 * 4);
  float*    wctx     = (float*)alloc((size_t)40 * 128 * 768 * 4);
  ushort_t* cat      = (ushort_t*)alloc((size_t)5120 * 3072 * 2);
  ushort_t* x_bf     = (ushort_t*)alloc((size_t)20 * 4000 * 768 * 2);      // 123 MB t-major
  ushort_t* pre      = (ushort_t*)alloc((size_t)20 * 250 * 50 * 256 * 2);  // 128 MB bf16

  prep_weights<<<512, 256, 0, stream>>>(Wih_f, Wih_b, Whh_f, Whh_b, bih_f, bhh_f, bih_b, bhh_b,
                                        projW, attpW, wihcat, whhcat, biascat, projw_bf, attpw_bf);
  convert_x_t<<<2048, 256, 0, stream>>>((const float4*)cmn, x_bf);

  // pre = x @ Wih^T + (bih+bhh), stored in recurrence lane-layout (bf16)
  gemm128<0><<<dim3(625, 7), 256, 0, stream>>>(x_bf, 768, wihcat, 768, 80000, 800, 12,
                                               biascat, nullptr, (float*)pre, 0);
  // fused 20-step bidirectional recurrence
  lstm_recur<<<dim3(250, 2), 256, 0, stream>>>(pre, whhcat, hcat);

  // cs = relu(hcat @ projW^T + projb)  [4000][768]
  gemm128<1><<<dim3(32, 6), 256, 0, stream>>>(hcat, 256, projw_bf, 256, 4000, 768, 4,
                                              projb, nullptr, cs, 768);
  rowdot<<<5120, 64, 0, stream>>>(bert, 768, W1w, W1b, part1, 5120);
  rowdot<<<4000, 64, 0, stream>>>(cs, 768, W2w, W2b, part2, 4000);
  bertw3_k<<<1024, 256, 0, stream>>>(bert, W3, bertW3);
  // total[b,s,p] = part1 + part2 + bertW3@cs^T + masks
  bgemm<1, 1><<<dim3(4, 4, 40), dim3(16, 16), 0, stream>>>(
      bertW3, 98304LL, 768, cs, 76800LL, 768, total_s, 12800LL, 100,
      128, 100, 768, part1, part2, amask, cmask);
  softmax_p<<<5120, 64, 0, stream>>>(total_s, cs_att);
  softmax_s<<<4000, 64, 0, stream>>>(total_s, ctx_att);
  // weight_cs = cs_att @ cs
  bgemm<0, 0><<<dim3(24, 4, 40), dim3(16, 16), 0, stream>>>(
      cs_att, 12800LL, 100, cs, 76800LL, 768, wcs, 98304LL, 768,
      128, 768, 100, nullptr, nullptr, nullptr, nullptr);
  // probs = cs_att @ ctx_att^T
  bgemm<1, 0><<<dim3(4, 4, 40), dim3(16, 16), 0, stream>>>(
      cs_att, 12800LL, 100, ctx_att, 12800LL, 100, probs, 16384LL, 128,
      128, 128, 100, nullptr, nullptr, nullptr, nullptr);
  // weighted_context = probs @ bert
  bgemm<0, 0><<<dim3(24, 4, 40), dim3(16, 16), 0, stream>>>(
      probs, 16384LL, 128, bert, 98304LL, 768, wctx, 98304LL, 768,
      128, 768, 128, nullptr, nullptr, nullptr, nullptr);
  catk<<<2048, 256, 0, stream>>>(bert, wcs, wctx, cat);
  // x = relu(cat @ attpW^T + attpb) + bert  -> d_out, then LN in place
  gemm128<2><<<dim3(40, 6), 256, 0, stream>>>(cat, 3072, attpw_bf, 3072, 5120, 768, 48,
                                              attpb, bert, (float*)d_out, 768);
  layernorm<<<5120, 256, 0, stream>>>((float*)d_out, lnw, lnb);
}

// Round 4
// 668.219 us; speedup vs baseline: 1.7068x; 1.0085x over previous
//
#include <hip/hip_runtime.h>

// QANet attention layer on MI355X (gfx950).
// B=40,S=128,H=768, NP=100, PL=20, HID=100, N=4000 sequences.
// Round 4: pre-GEMM fused with f32->bf16 conversion (reads commonsense f32
// directly, reg-staged swizzled LDS, prefetch regs overlap MFMA) + bijective
// XCD-chunked block mapping so A-panels are reused within one XCD's L2.

typedef unsigned short ushort_t;
typedef unsigned int u32;
typedef __attribute__((ext_vector_type(8))) short short8;
typedef __attribute__((ext_vector_type(4))) float f32x4;
typedef __attribute__((address_space(1))) const u32 gu32;
typedef __attribute__((address_space(3))) u32 lu32;

__device__ __forceinline__ ushort_t f2bf(float f) {
  u32 x = __builtin_bit_cast(u32, f);
  u32 r = (x + 0x7fffu + ((x >> 16) & 1u)) >> 16;
  return (ushort_t)r;
}
__device__ __forceinline__ float bflo(u32 u) { return __builtin_bit_cast(float, u << 16); }
__device__ __forceinline__ float bfhi(u32 u) { return __builtin_bit_cast(float, u & 0xffff0000u); }

__device__ __forceinline__ float sigm(float x) { return 1.f / (1.f + __expf(-x)); }
__device__ __forceinline__ float tanh_f(float x) { return 1.f - 2.f / (__expf(2.f * x) + 1.f); }

// ---------------- prep kernels ----------------

__global__ void prep_weights(const float* __restrict__ Wih_f, const float* __restrict__ Wih_b,
                             const float* __restrict__ Whh_f, const float* __restrict__ Whh_b,
                             const float* __restrict__ bih_f, const float* __restrict__ bhh_f,
                             const float* __restrict__ bih_b, const float* __restrict__ bhh_b,
                             const float* __restrict__ projW, const float* __restrict__ attpW,
                             ushort_t* __restrict__ wihcat, ushort_t* __restrict__ whhcat,
                             float* __restrict__ biascat, ushort_t* __restrict__ projw_bf,
                             ushort_t* __restrict__ attpw_bf) {
  const int TOT = 614400 + 102400 + 800 + 196608 + 2359296;
  for (int idx = blockIdx.x * 256 + threadIdx.x; idx < TOT; idx += gridDim.x * 256) {
    if (idx < 614400) {                       // Wih cat [800][768]
      int g = idx / 768, k = idx % 768;
      float v = g < 400 ? Wih_f[g * 768 + k] : Wih_b[(g - 400) * 768 + k];
      wihcat[idx] = f2bf(v);
    } else if (idx < 716800) {                // Whh cat padded [2][400][128]
      int e = idx - 614400; int g = e / 128, j = e % 128;
      float v = 0.f;
      if (j < 100) v = g < 400 ? Whh_f[g * 100 + j] : Whh_b[(g - 400) * 100 + j];
      whhcat[e] = f2bf(v);
    } else if (idx < 717600) {                // bias cat [800]
      int g = idx - 716800;
      biascat[g] = g < 400 ? bih_f[g] + bhh_f[g] : bih_b[g - 400] + bhh_b[g - 400];
    } else if (idx < 914208) {                // projW padded [768][256]
      int e = idx - 717600; int o = e / 256, j = e % 256;
      float v = 0.f;
      if (j < 100) v = projW[o * 200 + j];
      else if (j >= 128 && j < 228) v = projW[o * 200 + 100 + (j - 128)];
      projw_bf[e] = f2bf(v);
    } else {                                  // attpW [768][3072]
      int e = idx - 914208;
      attpw_bf[e] = f2bf(attpW[e]);
    }
  }
}

// ---------------- fused convert + pre GEMM ----------------
// P[t][seqchunk][nq][off] = (x @ Wih^T + bias) bf16, off = s*16+lk*4+r.
// A read as f32 from commonsense [4000][20][768]; row m = t*4000+seq.
// Reg-staged A (f32->bf16 convert) + B; prefetch kt+1 after the drain barrier
// so HBM latency hides under MFMA. XCD-chunked bijective block swizzle:
// logical L orders bn fastest -> the 7 blocks sharing an A panel share an XCD.

__global__ __launch_bounds__(256) void gemm_pre(
    const float* __restrict__ X,        // [4000][20][768] f32
    const ushort_t* __restrict__ B,     // wihcat [800][768]
    const float* __restrict__ bias,     // [800]
    ushort_t* __restrict__ P)
{
  __shared__ __align__(16) ushort_t lsA[128 * 64];
  __shared__ __align__(16) ushort_t lsB[128 * 64];
  // bijective XCD chunking: nwg=4375, q=546, r=7
  int bid = blockIdx.x;
  int xcd = bid & 7, slot = bid >> 3;
  int L = (xcd < 7) ? xcd * 547 + slot : 3829 + slot;
  int bm = L / 7, bn = L - bm * 7;
  int m0 = bm * 128, n0 = bn * 128;
  int tid = threadIdx.x, lane = tid & 63, w = tid >> 6;
  int wr = w >> 1, wc = w & 1;
  int l15 = lane & 15, lk = lane >> 4;
  f32x4 acc[4][4];
  #pragma unroll
  for (int i = 0; i < 4; ++i)
    #pragma unroll
    for (int j = 0; j < 4; ++j)
      #pragma unroll
      for (int r = 0; r < 4; ++r) acc[i][j][r] = 0.f;

  int srow = tid >> 3, ss = tid & 7;   // 4 slots/thread: rows srow+32i, slot ss
  size_t abase[4];
  const ushort_t* bbase[4];
  bool bok[4];
  #pragma unroll
  for (int i = 0; i < 4; ++i) {
    int m = m0 + srow + 32 * i;
    int t = m / 4000, sq = m - t * 4000;
    abase[i] = ((size_t)sq * 20 + t) * 768;
    int n = n0 + srow + 32 * i;
    bok[i] = n < 800;
    bbase[i] = B + (size_t)(bok[i] ? n : 0) * 768;
  }

  float4 pa[4][2];
  uint4 pb[4];
  auto load_stage = [&](int kt) {
    #pragma unroll
    for (int i = 0; i < 4; ++i) {
      const float* ap = X + abase[i] + kt * 64 + ss * 8;
      pa[i][0] = *reinterpret_cast<const float4*>(ap);
      pa[i][1] = *reinterpret_cast<const float4*>(ap + 4);
      uint4 bv = {0u, 0u, 0u, 0u};
      if (bok[i]) bv = *reinterpret_cast<const uint4*>(bbase[i] + kt * 64 + ss * 8);
      pb[i] = bv;
    }
  };
  load_stage(0);

  for (int kt = 0; kt < 12; ++kt) {
    __syncthreads();    // previous MFMA reads done (also drains prefetch loads)
    #pragma unroll
    for (int i = 0; i < 4; ++i) {
      int row = srow + 32 * i;
      int ph = (ss ^ (row & 7)) << 3;
      ushort4 lo, hi;
      lo.x = f2bf(pa[i][0].x); lo.y = f2bf(pa[i][0].y);
      lo.z = f2bf(pa[i][0].z); lo.w = f2bf(pa[i][0].w);
      hi.x = f2bf(pa[i][1].x); hi.y = f2bf(pa[i][1].y);
      hi.z = f2bf(pa[i][1].z); hi.w = f2bf(pa[i][1].w);
      *reinterpret_cast<ushort4*>(&lsA[row * 64 + ph]) = lo;
      *reinterpret_cast<ushort4*>(&lsA[row * 64 + ph + 4]) = hi;
      *reinterpret_cast<uint4*>(&lsB[row * 64 + ph]) = pb[i];
    }
    __syncthreads();    // ds_writes visible
    if (kt < 11) load_stage(kt + 1);   // overlap with MFMA below
    #pragma unroll
    for (int ks = 0; ks < 2; ++ks) {
      short8 af[4], bfv[4];
      #pragma unroll
      for (int f = 0; f < 4; ++f) {
        int row = wr * 64 + f * 16 + l15;
        af[f] = *reinterpret_cast<const short8*>(
            &lsA[row * 64 + (((ks * 4 + lk) ^ (row & 7)) << 3)]);
        int rowb = wc * 64 + f * 16 + l15;
        bfv[f] = *reinterpret_cast<const short8*>(
            &lsB[rowb * 64 + (((ks * 4 + lk) ^ (rowb & 7)) << 3)]);
      }
      #pragma unroll
      for (int fm = 0; fm < 4; ++fm)
        #pragma unroll
        for (int fn = 0; fn < 4; ++fn)
          acc[fm][fn] = __builtin_amdgcn_mfma_f32_16x16x32_bf16(af[fm], bfv[fn], acc[fm][fn], 0, 0, 0);
    }
  }
  // store in recurrence lane-layout (16-row fragments never straddle t: 4000%16==0)
  #pragma unroll
  for (int fm = 0; fm < 4; ++fm) {
    int mb = m0 + wr * 64 + fm * 16;
    int t = mb / 4000;
    int sq = mb - t * 4000;
    int cch = sq >> 4;
    #pragma unroll
    for (int fn = 0; fn < 4; ++fn) {
      int nb = n0 + wc * 64 + fn * 16;
      if (nb < 800) {
        int nl = nb < 400 ? nb : nb - 400;
        int nq = (nb < 400 ? 0 : 25) + (nl >> 4);
        float bsv = bias[nb + l15];
        ushort4 pk;
        pk.x = f2bf(acc[fm][fn][0] + bsv);
        pk.y = f2bf(acc[fm][fn][1] + bsv);
        pk.z = f2bf(acc[fm][fn][2] + bsv);
        pk.w = f2bf(acc[fm][fn][3] + bsv);
        *reinterpret_cast<ushort4*>(
            &P[((((size_t)t * 250 + cch) * 50 + nq) << 8) + l15 * 16 + lk * 4]) = pk;
      }
    }
  }
}

// ---------------- 128x128 MFMA GEMM (global_load_lds) ----------------
// EPI 1: relu(v+bias); EPI 2: relu(v+bias)+resid.
// nbn>0: linear grid + bijective XCD-chunk swizzle (bn fastest within bm).

template <int EPI>
__global__ __launch_bounds__(256) void gemm128(
    const ushort_t* __restrict__ A, int lda,
    const ushort_t* __restrict__ B, int ldb,
    int M, int N, int KT,
    const float* __restrict__ bias,
    const float* __restrict__ resid,
    float* __restrict__ C, int ldc,
    int nbn, int swq, int swr)
{
  __shared__ __align__(16) ushort_t lsA[128 * 64];
  __shared__ __align__(16) ushort_t lsB[128 * 64];
  int bm, bn;
  if (nbn > 0) {
    int bid = blockIdx.x, xcd = bid & 7, slot = bid >> 3;
    int L = (xcd < swr) ? xcd * (swq + 1) + slot
                        : swr * (swq + 1) + (xcd - swr) * swq + slot;
    bm = L / nbn; bn = L - bm * nbn;
  } else {
    bm = blockIdx.x; bn = blockIdx.y;
  }
  int m0 = bm * 128, n0 = bn * 128;
  int tid = threadIdx.x, lane = tid & 63, w = tid >> 6;
  int wr = w >> 1, wc = w & 1;
  int l15 = lane & 15, lk = lane >> 4;
  f32x4 acc[4][4];
  #pragma unroll
  for (int i = 0; i < 4; ++i)
    #pragma unroll
    for (int j = 0; j < 4; ++j)
      #pragma unroll
      for (int r = 0; r < 4; ++r) acc[i][j][r] = 0.f;

  int r_in = lane >> 3, p = lane & 7;
  for (int kt = 0; kt < KT; ++kt) {
    __syncthreads();
    #pragma unroll
    for (int i = 0; i < 4; ++i) {
      int seg = w * 4 + i;
      int row = seg * 8 + r_in;
      int sl = p ^ (row & 7);
      int m = m0 + row;
      if (m < M)
        __builtin_amdgcn_global_load_lds(
            (gu32*)(A + (size_t)m * lda + kt * 64 + sl * 8),
            (lu32*)(lsA + seg * 512), 16, 0, 0);
      int n = n0 + row;
      if (n < N)
        __builtin_amdgcn_global_load_lds(
            (gu32*)(B + (size_t)n * ldb + kt * 64 + sl * 8),
            (lu32*)(lsB + seg * 512), 16, 0, 0);
    }
    __syncthreads();
    #pragma unroll
    for (int ks = 0; ks < 2; ++ks) {
      short8 af[4], bfv[4];
      #pragma unroll
      for (int f = 0; f < 4; ++f) {
        int row = wr * 64 + f * 16 + l15;
        af[f] = *reinterpret_cast<const short8*>(
            &lsA[row * 64 + (((ks * 4 + lk) ^ (row & 7)) << 3)]);
        int rowb = wc * 64 + f * 16 + l15;
        bfv[f] = *reinterpret_cast<const short8*>(
            &lsB[rowb * 64 + (((ks * 4 + lk) ^ (rowb & 7)) << 3)]);
      }
      #pragma unroll
      for (int fm = 0; fm < 4; ++fm)
        #pragma unroll
        for (int fn = 0; fn < 4; ++fn)
          acc[fm][fn] = __builtin_amdgcn_mfma_f32_16x16x32_bf16(af[fm], bfv[fn], acc[fm][fn], 0, 0, 0);
    }
  }
  #pragma unroll
  for (int fm = 0; fm < 4; ++fm)
    #pragma unroll
    for (int fn = 0; fn < 4; ++fn)
      #pragma unroll
      for (int r = 0; r < 4; ++r) {
        int m = m0 + wr * 64 + fm * 16 + lk * 4 + r;
        int n = n0 + wc * 64 + fn * 16 + l15;
        if (m < M && n < N) {
          float v = acc[fm][fn][r] + bias[n];
          v = fmaxf(v, 0.f);
          if (EPI == 2) v += resid[(size_t)m * ldc + n];
          C[(size_t)m * ldc + n] = v;
        }
      }
}

// ---------------- fused biLSTM recurrence ----------------

__global__ __launch_bounds__(256) void lstm_recur(
    const ushort_t* __restrict__ pre,    // [20][250][50][256] bf16
    const ushort_t* __restrict__ whh,    // [2][400][128] bf16 (k-padded)
    ushort_t* __restrict__ hcat)         // [4000][256] bf16
{
  __shared__ __align__(16) ushort_t gx[25 * 256];     // gate exchange
  __shared__ __align__(16) ushort_t h_lds[16 * 128];  // h, swizzled slot^row

  int dir = blockIdx.y;
  int c = blockIdx.x;                   // seq chunk (16 seqs)
  int tid = threadIdx.x, lane = tid & 63, w = tid >> 6;
  int s = lane & 15, lk = lane >> 4;

  short8 wf[7][4];
  #pragma unroll
  for (int qi = 0; qi < 7; ++qi) {
    int q = w + qi * 4;
    if (q < 25) {
      const ushort_t* wp = whh + ((size_t)dir * 400 + q * 16 + s) * 128;
      #pragma unroll
      for (int ks = 0; ks < 4; ++ks)
        wf[qi][ks] = *reinterpret_cast<const short8*>(wp + ks * 32 + lk * 8);
    }
  }
  for (int e = tid; e < 1024; e += 256)
    *reinterpret_cast<u32*>(&h_lds[e * 2]) = 0u;

  float cst[2][4];
  #pragma unroll
  for (int g = 0; g < 2; ++g)
    #pragma unroll
    for (int r = 0; r < 4; ++r) cst[g][r] = 0.f;

  uint2 pvA[7], pvB[7];
  {
    int tt0 = dir ? 19 : 0;
    const ushort_t* pb = pre + ((((size_t)tt0 * 250 + c) * 50 + dir * 25) << 8);
    #pragma unroll
    for (int qi = 0; qi < 7; ++qi) {
      int q = w + qi * 4;
      if (q < 25) pvA[qi] = *reinterpret_cast<const uint2*>(pb + (q << 8) + s * 16 + lk * 4);
    }
  }
  __syncthreads();

  auto step = [&](uint2 (&pvc)[7], uint2 (&pvn)[7], int t) {
    f32x4 acc[7];
    #pragma unroll
    for (int qi = 0; qi < 7; ++qi)
      #pragma unroll
      for (int r = 0; r < 4; ++r) acc[qi][r] = 0.f;
    #pragma unroll
    for (int ks = 0; ks < 4; ++ks) {
      short8 af = *reinterpret_cast<const short8*>(
          &h_lds[s * 128 + (((ks * 4 + lk) ^ s) << 3)]);
      #pragma unroll
      for (int qi = 0; qi < 7; ++qi)
        if (w + qi * 4 < 25)
          acc[qi] = __builtin_amdgcn_mfma_f32_16x16x32_bf16(af, wf[qi][ks], acc[qi], 0, 0, 0);
    }
    #pragma unroll
    for (int qi = 0; qi < 7; ++qi)
      if (w + qi * 4 < 25) {
        acc[qi][0] += bflo(pvc[qi].x); acc[qi][1] += bfhi(pvc[qi].x);
        acc[qi][2] += bflo(pvc[qi].y); acc[qi][3] += bfhi(pvc[qi].y);
      }
    if (t + 1 < 20) {
      int tn = dir ? 19 - (t + 1) : (t + 1);
      const ushort_t* pb = pre + ((((size_t)tn * 250 + c) * 50 + dir * 25) << 8);
      #pragma unroll
      for (int qi = 0; qi < 7; ++qi) {
        int q = w + qi * 4;
        if (q < 25) pvn[qi] = *reinterpret_cast<const uint2*>(pb + (q << 8) + s * 16 + lk * 4);
      }
    }
    #pragma unroll
    for (int qi = 0; qi < 7; ++qi) {
      int q = w + qi * 4;
      if (q < 25) {
        ushort4 pk;
        pk.x = f2bf(acc[qi][0]); pk.y = f2bf(acc[qi][1]);
        pk.z = f2bf(acc[qi][2]); pk.w = f2bf(acc[qi][3]);
        *reinterpret_cast<ushort4*>(&gx[(q << 8) + s * 16 + lk * 4]) = pk;
      }
    }
    __syncthreads();
    #pragma unroll
    for (int gd = 0; gd < 2; ++gd) {
      int gi = w + gd * 4;
      if (gi < 7) {
        int j = gi * 16 + s;
        if (j < 100) {
          auto ld2 = [&](int q, int sp) {
            return *reinterpret_cast<const uint2*>(&gx[(q << 8) + sp * 16 + lk * 4]);
          };
          uint2 iv = ld2(gi, s);
          uint2 fv = (s < 12) ? ld2(6 + gi, s + 4) : ld2(7 + gi, s - 12);
          uint2 gv = (s < 8) ? ld2(12 + gi, s + 8) : ld2(13 + gi, s - 8);
          uint2 ov = (s < 4) ? ld2(18 + gi, s + 12) : ld2(19 + gi, s - 4);
          float ia[4] = {bflo(iv.x), bfhi(iv.x), bflo(iv.y), bfhi(iv.y)};
          float fa[4] = {bflo(fv.x), bfhi(fv.x), bflo(fv.y), bfhi(fv.y)};
          float ga[4] = {bflo(gv.x), bfhi(gv.x), bflo(gv.y), bfhi(gv.y)};
          float oa[4] = {bflo(ov.x), bfhi(ov.x), bflo(ov.y), bfhi(ov.y)};
          #pragma unroll
          for (int r = 0; r < 4; ++r) {
            float cc = sigm(fa[r]) * cst[gd][r] + sigm(ia[r]) * tanh_f(ga[r]);
            cst[gd][r] = cc;
            int row = lk * 4 + r;
            h_lds[row * 128 + (((j >> 3) ^ row) << 3) + (j & 7)] =
                f2bf(sigm(oa[r]) * tanh_f(cc));
          }
        }
      }
    }
    __syncthreads();
  };

  #pragma unroll 1
  for (int tp = 0; tp < 10; ++tp) {
    step(pvA, pvB, 2 * tp);
    step(pvB, pvA, 2 * tp + 1);
  }

  {
    int row = tid >> 4, sl = tid & 15;
    uint2 v = *reinterpret_cast<const uint2*>(&h_lds[row * 128 + ((sl ^ row) << 3)]);
    *reinterpret_cast<uint2*>(&hcat[(size_t)(c * 16 + row) * 256 + dir * 128 + sl * 8]) = v;
  }
}

// ---------------- small f32 kernels ----------------

__global__ void rowdot(const float* __restrict__ X, int ld, const float* __restrict__ w,
                       const float* __restrict__ b0, float* __restrict__ out, int nrows) {
  int row = blockIdx.x;
  if (row >= nrows) return;
  int lane = threadIdx.x;   // 64
  const float* x = X + (size_t)row * ld;
  float s = 0.f;
  for (int k = lane; k < 768; k += 64) s += x[k] * w[k];
  for (int off = 32; off; off >>= 1) s += __shfl_down(s, off);
  if (lane == 0) out[row] = s + b0[0];
}

__global__ void bertw3_k(const float* __restrict__ bert, const float* __restrict__ W3,
                         float* __restrict__ out) {
  const int TOT = 40 * 128 * 768;
  for (int i = blockIdx.x * 256 + threadIdx.x; i < TOT; i += gridDim.x * 256)
    out[i] = bert[i] * W3[i % 768];
}

template <int TRANSB, int EPI>
__global__ __launch_bounds__(256) void bgemm(
    const float* __restrict__ A, long long sA, int lda,
    const float* __restrict__ B, long long sB, int ldb,
    float* __restrict__ C, long long sC, int ldc,
    int M, int N, int K,
    const float* __restrict__ p1, const float* __restrict__ p2,
    const int* __restrict__ amask, const int* __restrict__ cmask) {
  int b = blockIdx.z;
  __shared__ float As[32][33], Bs[32][33];
  int tx = threadIdx.x, ty = threadIdx.y;
  int t = ty * 16 + tx;
  int n0 = blockIdx.x * 32, m0 = blockIdx.y * 32;
  const float* Ab = A + (size_t)b * sA;
  const float* Bb = B + (size_t)b * sB;
  float c00 = 0, c01 = 0, c10 = 0, c11 = 0;
  for (int k0 = 0; k0 < K; k0 += 32) {
    __syncthreads();
    #pragma unroll
    for (int i = 0; i < 4; ++i) {
      int e = t + i * 256;
      int r = e >> 5, q = e & 31;
      {
        int m = m0 + r, k = k0 + q;
        As[r][q] = (m < M && k < K) ? Ab[(size_t)m * lda + k] : 0.f;
      }
      if (TRANSB) {
        int n = n0 + r, k = k0 + q;
        Bs[q][r] = (n < N && k < K) ? Bb[(size_t)n * ldb + k] : 0.f;
      } else {
        int k = k0 + r, n = n0 + q;
        Bs[r][q] = (k < K && n < N) ? Bb[(size_t)k * ldb + n] : 0.f;
      }
    }
    __syncthreads();
    #pragma unroll 8
    for (int k = 0; k < 32; ++k) {
      float a0 = As[ty][k], a1 = As[ty + 16][k];
      float b0 = Bs[k][tx], b1 = Bs[k][tx + 16];
      c00 += a0 * b0; c01 += a0 * b1;
      c10 += a1 * b0; c11 += a1 * b1;
    }
  }
  float cc[2][2] = {{c00, c01}, {c10, c11}};
  #pragma unroll
  for (int i = 0; i < 2; ++i)
    #pragma unroll
    for (int j = 0; j < 2; ++j) {
      int m = m0 + ty + 16 * i, n = n0 + tx + 16 * j;
      if (m < M && n < N) {
        float v = cc[i][j];
        if (EPI == 1) {
          v += p1[b * M + m] + p2[b * N + n];
          v += (1.f - (float)amask[b * M + m]) * -10000.f;
          v += (1.f - (float)cmask[b * N + n]) * -10000.f;
        }
        C[(size_t)b * sC + (size_t)m * ldc + n] = v;
      }
    }
}

__global__ void softmax_p(const float* __restrict__ total, float* __restrict__ out) {
  int row = blockIdx.x;   // 5120
  int lane = threadIdx.x; // 64
  const float* x = total + (size_t)row * 100;
  float e0 = x[lane];
  bool has1 = (lane + 64) < 100;
  float e1 = has1 ? x[lane + 64] : -3.4e38f;
  float m = fmaxf(e0, e1);
  for (int off = 32; off; off >>= 1) m = fmaxf(m, __shfl_xor(m, off));
  float s0 = expf(e0 - m), s1 = has1 ? expf(e1 - m) : 0.f;
  float s = s0 + s1;
  for (int off = 32; off; off >>= 1) s += __shfl_xor(s, off);
  float inv = 1.f / s;
  float* o = out + (size_t)row * 100;
  o[lane] = s0 * inv;
  if (has1) o[lane + 64] = s1 * inv;
}

__global__ void softmax_s(const float* __restrict__ total, float* __restrict__ out) {
  int col = blockIdx.x;   // 4000
  int b = col / 100, p = col - b * 100;
  int lane = threadIdx.x;
  const float* base = total + (size_t)b * 12800 + p;
  float e0 = base[lane * 100], e1 = base[(lane + 64) * 100];
  float m = fmaxf(e0, e1);
  for (int off = 32; off; off >>= 1) m = fmaxf(m, __shfl_xor(m, off));
  float s0 = expf(e0 - m), s1 = expf(e1 - m);
  float s = s0 + s1;
  for (int off = 32; off; off >>= 1) s += __shfl_xor(s, off);
  float inv = 1.f / s;
  float* o = out + (size_t)b * 12800 + p;
  o[lane * 100] = s0 * inv;
  o[(lane + 64) * 100] = s1 * inv;
}

__global__ void catk(const float* __restrict__ bert, const float* __restrict__ wcs,
                     const float* __restrict__ wctx, ushort_t* __restrict__ cat) {
  const int TOT = 5120 * 3072;
  for (int i = blockIdx.x * 256 + threadIdx.x; i < TOT; i += gridDim.x * 256) {
    int row = i / 3072, col = i - row * 3072;
    int seg = col / 768;
    int h = col - seg * 768;
    size_t e = (size_t)row * 768 + h;
    float v;
    if (seg == 0) v = bert[e];
    else if (seg == 1) v = wcs[e];
    else if (seg == 2) v = bert[e] * wcs[e];
    else v = bert[e] * wctx[e];
    cat[i] = f2bf(v);
  }
}

__global__ __launch_bounds__(256) void layernorm(float* __restrict__ X,
                                                 const float* __restrict__ w,
                                                 const float* __restrict__ bta) {
  int row = blockIdx.x;   // 5120
  float* x = X + (size_t)row * 768;
  int t = threadIdx.x;
  float v[3];
  float s = 0.f;
  #pragma unroll
  for (int i = 0; i < 3; ++i) { v[i] = x[t + 256 * i]; s += v[i]; }
  __shared__ float red[256];
  red[t] = s; __syncthreads();
  for (int off = 128; off; off >>= 1) { if (t < off) red[t] += red[t + off]; __syncthreads(); }
  float mean = red[0] * (1.f / 768.f);
  __syncthreads();
  float q = 0.f;
  #pragma unroll
  for (int i = 0; i < 3; ++i) { float d = v[i] - mean; q += d * d; }
  red[t] = q; __syncthreads();
  for (int off = 128; off; off >>= 1) { if (t < off) red[t] += red[t + off]; __syncthreads(); }
  float inv = rsqrtf(red[0] * (1.f / 768.f) + 1e-12f);
  #pragma unroll
  for (int i = 0; i < 3; ++i) {
    int k = t + 256 * i;
    x[k] = w[k] * ((v[i] - mean) * inv) + bta[k];
  }
}

// ---------------- host orchestration ----------------

extern "C" void kernel_launch(void* const* d_in, const int* in_sizes, int n_in,
                              void* d_out, int out_size, void* d_ws, size_t ws_size,
                              hipStream_t stream) {
  (void)in_sizes; (void)n_in; (void)out_size; (void)ws_size;
  const float* bert  = (const float*)d_in[0];
  const float* cmn   = (const float*)d_in[1];
  const int*   amask = (const int*)d_in[2];
  const int*   cmask = (const int*)d_in[3];
  const float* Wih_f = (const float*)d_in[8];
  const float* Whh_f = (const float*)d_in[9];
  const float* bih_f = (const float*)d_in[10];
  const float* bhh_f = (const float*)d_in[11];
  const float* Wih_b = (const float*)d_in[12];
  const float* Whh_b = (const float*)d_in[13];
  const float* bih_b = (const float*)d_in[14];
  const float* bhh_b = (const float*)d_in[15];
  const float* projW = (const float*)d_in[16];
  const float* projb = (const float*)d_in[17];
  const float* W1w   = (const float*)d_in[18];
  const float* W1b   = (const float*)d_in[19];
  const float* W2w   = (const float*)d_in[20];
  const float* W2b   = (const float*)d_in[21];
  const float* W3    = (const float*)d_in[22];
  const float* attpW = (const float*)d_in[23];
  const float* attpb = (const float*)d_in[24];
  const float* lnw   = (const float*)d_in[25];
  const float* lnb   = (const float*)d_in[26];

  char* base = (char*)d_ws;
  size_t off = 0;
  auto alloc = [&](size_t bytes) -> char* {
    char* r = base + off;
    off += (bytes + 255) & ~(size_t)255;
    return r;
  };
  ushort_t* wihcat   = (ushort_t*)alloc(800 * 768 * 2);
  ushort_t* whhcat   = (ushort_t*)alloc(800 * 128 * 2);
  float*    biascat  = (float*)alloc(800 * 4);
  ushort_t* projw_bf = (ushort_t*)alloc(768 * 256 * 2);
  ushort_t* attpw_bf = (ushort_t*)alloc(768 * 3072 * 2);
  ushort_t* hcat     = (ushort_t*)alloc(4000 * 256 * 2);
  float*    cs       = (float*)alloc((size_t)4000 * 768 * 4);
  float*    part1    = (float*)alloc(5120 * 4);
  float*    part2    = (float*)alloc(4000 * 4);
  float*    total_s  = (float*)alloc((size_t)40 * 128 * 100 * 4);
  float*    cs_att   = (float*)alloc((size_t)40 * 128 * 100 * 4);
  float*    ctx_att  = (float*)alloc((size_t)40 * 128 * 100 * 4);
  float*    bertW3   = (float*)alloc((size_t)40 * 128 * 768 * 4);
  float*    probs    = (float*)alloc((size_t)40 * 128 * 128 * 4);
  float*    wcs      = (float*)alloc((size_t)40 * 128 * 768 * 4);
  float*    wctx     = (float*)alloc((size_t)40 * 128 * 768 * 4);
  ushort_t* cat      = (ushort_t*)alloc((size_t)5120 * 3072 * 2);
  ushort_t* pre      = (ushort_t*)alloc((size_t)20 * 250 * 50 * 256 * 2);  // 128 MB bf16

  prep_weights<<<512, 256, 0, stream>>>(Wih_f, Wih_b, Whh_f, Whh_b, bih_f, bhh_f, bih_b, bhh_b,
                                        projW, attpW, wihcat, whhcat, biascat, projw_bf, attpw_bf);

  // pre = x @ Wih^T + (bih+bhh), fused f32->bf16 conversion, XCD-chunked
  gemm_pre<<<4375, 256, 0, stream>>>(cmn, wihcat, biascat, pre);
  // fused 20-step bidirectional recurrence
  lstm_recur<<<dim3(250, 2), 256, 0, stream>>>(pre, whhcat, hcat);

  // cs = relu(hcat @ projW^T + projb)  [4000][768]
  gemm128<1><<<dim3(32, 6), 256, 0, stream>>>(hcat, 256, projw_bf, 256, 4000, 768, 4,
                                              projb, nullptr, cs, 768, 0, 0, 0);
  rowdot<<<5120, 64, 0, stream>>>(bert, 768, W1w, W1b, part1, 5120);
  rowdot<<<4000, 64, 0, stream>>>(cs, 768, W2w, W2b, part2, 4000);
  bertw3_k<<<1024, 256, 0, stream>>>(bert, W3, bertW3);
  // total[b,s,p] = part1 + part2 + bertW3@cs^T + masks
  bgemm<1, 1><<<dim3(4, 4, 40), dim3(16, 16), 0, stream>>>(
      bertW3, 98304LL, 768, cs, 76800LL, 768, total_s, 12800LL, 100,
      128, 100, 768, part1, part2, amask, cmask);
  softmax_p<<<5120, 64, 0, stream>>>(total_s, cs_att);
  softmax_s<<<4000, 64, 0, stream>>>(total_s, ctx_att);
  // weight_cs = cs_att @ cs
  bgemm<0, 0><<<dim3(24, 4, 40), dim3(16, 16), 0, stream>>>(
      cs_att, 12800LL, 100, cs, 76800LL, 768, wcs, 98304LL, 768,
      128, 768, 100, nullptr, nullptr, nullptr, nullptr);
  // probs = cs_att @ ctx_att^T
  bgemm<1, 0><<<dim3(4, 4, 40), dim3(16, 16), 0, stream>>>(
      cs_att, 12800LL, 100, ctx_att, 12800LL, 100, probs, 16384LL, 128,
      128, 128, 100, nullptr, nullptr, nullptr, nullptr);
  // weighted_context = probs @ bert
  bgemm<0, 0><<<dim3(24, 4, 40), dim3(16, 16), 0, stream>>>(
      probs, 16384LL, 128, bert, 98304LL, 768, wctx, 98304LL, 768,
      128, 768, 128, nullptr, nullptr, nullptr, nullptr);
  catk<<<2048, 256, 0, stream>>>(bert, wcs, wctx, cat);
  // x = relu(cat @ attpW^T + attpb) + bert  -> d_out, then LN in place
  gemm128<2><<<240, 256, 0, stream>>>(cat, 3072, attpw_bf, 3072, 5120, 768, 48,
                                      attpb, bert, (float*)d_out, 768, 6, 30, 0);
  layernorm<<<5120, 256, 0, stream>>>((float*)d_out, lnw, lnb);
}